// Round 2
// baseline (6855.106 us; speedup 1.0000x reference)
//
#include <hip/hip_runtime.h>
#include <hip/hip_bf16.h>
#include <math.h>

#define NS0 50000
#define NS1 12500
#define NS2 3125
#define NS3 800
#define NS4 200
#define BATCH 32
#define SLEN 9

typedef __hip_bfloat16 bf16;

__device__ inline float ldf(const float* p) { return *p; }
__device__ inline float ldf(const bf16* p)  { return __bfloat162float(*p); }
__device__ inline void stf(float* p, float v) { *p = v; }
__device__ inline void stf(bf16* p, float v)  { *p = __float2bfloat16(v); }

// ---------------- SpiralConv: gather + dense linear + (optional) ELU --------
// x: (B, N, CIN) ; idx: (N, S) ; W: (S*CIN, COUT) fp32 ; y: (B, N, COUT)
template<int CIN, int COUT, int TPR, int RPB, int ACT, typename TIN, typename TOUT>
__global__ void __launch_bounds__(256)
sconv_kernel(const TIN* __restrict__ x, const int* __restrict__ idx,
             const float* __restrict__ W, const float* __restrict__ bias,
             TOUT* __restrict__ y, int N)
{
    constexpr int KLEN = SLEN * CIN;
    __shared__ float lds[RPB][KLEN];
    const int t = threadIdx.x;
    const int row0 = blockIdx.x * RPB;
    const int totalRows = BATCH * N;

    // cooperative gather of RPB rows, each S*CIN values (convert to fp32 in LDS)
    for (int e = t; e < RPB * KLEN; e += 256) {
        int r = e / KLEN;
        int k = e - r * KLEN;
        int g = row0 + r;
        if (g < totalRows) {
            int b = g / N, n = g - b * N;
            int s = k / CIN, c = k - s * CIN;
            int j = idx[n * SLEN + s];
            lds[r][k] = ldf(&x[(b * N + j) * CIN + c]);
        }
    }
    __syncthreads();

    const int co = t % TPR;
    const int r  = t / TPR;
    const int g  = row0 + r;
    if (g < totalRows && co < COUT) {
        float acc = bias[co];
        const float* ldr = lds[r];
        #pragma unroll 4
        for (int k = 0; k < KLEN; ++k)
            acc = fmaf(ldr[k], W[k * COUT + co], acc);
        if (ACT) acc = acc > 0.f ? acc : expm1f(acc);
        stf(&y[g * COUT + co], acc);
    }
}

// ---------------- Pool (down or up): structured K=4 segment sum, bf16 -------
// y[b,m,c] = sum_{j<4} vals[4m+j] * x[b, cols[4m+j], c] ; 8 bf16 per thread
__global__ void __launch_bounds__(256)
pool_kernel(const bf16* __restrict__ x, const int* __restrict__ cols,
            const float* __restrict__ vals, bf16* __restrict__ y,
            int M, int Nin, int C8)
{
    int tid = blockIdx.x * 256 + threadIdx.x;
    int total = BATCH * M * C8;
    if (tid >= total) return;
    int c8 = tid % C8;
    int bm = tid / C8;
    int m = bm % M;
    int b = bm / M;
    float acc[8];
    #pragma unroll
    for (int e = 0; e < 8; ++e) acc[e] = 0.f;
    #pragma unroll
    for (int j = 0; j < 4; ++j) {
        int col = cols[m * 4 + j];
        float v = vals[m * 4 + j];
        uint4 u = ((const uint4*)x)[(b * Nin + col) * C8 + c8];
        const bf16* h = (const bf16*)&u;
        #pragma unroll
        for (int e = 0; e < 8; ++e)
            acc[e] = fmaf(v, __bfloat162float(h[e]), acc[e]);
    }
    uint4 o;
    bf16* oh = (bf16*)&o;
    #pragma unroll
    for (int e = 0; e < 8; ++e) oh[e] = __float2bfloat16(acc[e]);
    ((uint4*)y)[(b * M + m) * C8 + c8] = o;
}

// ---------------- mu = sigmoid(h @ muW + mub); writes z and mu outputs ------
// h: (B, 25600) bf16 ; W: (25600, 128) fp32 ; one block per b, 128 threads
__global__ void __launch_bounds__(128)
mu_kernel(const bf16* __restrict__ h, const float* __restrict__ W,
          const float* __restrict__ bias, float* __restrict__ z,
          float* __restrict__ out_z, float* __restrict__ out_mu)
{
    __shared__ float hs[128];
    const int b = blockIdx.x;
    const int co = threadIdx.x;
    const bf16* hb = h + b * 25600;
    float acc = bias[co];
    for (int k0 = 0; k0 < 25600; k0 += 128) {
        __syncthreads();
        hs[co] = __bfloat162float(hb[k0 + co]);
        __syncthreads();
        #pragma unroll 8
        for (int kk = 0; kk < 128; ++kk)
            acc = fmaf(hs[kk], W[(k0 + kk) * 128 + co], acc);
    }
    float m = 1.f / (1.f + expf(-acc));
    z[b * 128 + co] = m;
    out_z[b * 128 + co] = m;
    out_mu[b * 128 + co] = m;
}

// ---------------- d0 = z @ deW0 + deb0 : (32,128)@(128,25600) → bf16 --------
__global__ void __launch_bounds__(256)
de0_kernel(const float* __restrict__ z, const float* __restrict__ W,
           const float* __restrict__ bias, bf16* __restrict__ d)
{
    __shared__ float zs[BATCH * 128];
    const int t = threadIdx.x;
    for (int e = t; e < BATCH * 128; e += 256) zs[e] = z[e];
    __syncthreads();
    const int j = blockIdx.x * 256 + t;   // j in [0, 25600)
    float bj = bias[j];
    float acc[BATCH];
    #pragma unroll
    for (int b = 0; b < BATCH; ++b) acc[b] = bj;
    for (int k = 0; k < 128; ++k) {
        float w = W[k * 25600 + j];
        #pragma unroll
        for (int b = 0; b < BATCH; ++b)
            acc[b] = fmaf(zs[b * 128 + k], w, acc[b]);
    }
    #pragma unroll
    for (int b = 0; b < BATCH; ++b)
        d[b * 25600 + j] = __float2bfloat16(acc[b]);
}

extern "C" void kernel_launch(void* const* d_in, const int* in_sizes, int n_in,
                              void* d_out, int out_size, void* d_ws, size_t ws_size,
                              hipStream_t stream)
{
    const float* x = (const float*)d_in[0];
    const int*   sp[4];
    const int*   dn_cols[4];
    const float* dn_vals[4];
    const int*   up_cols[4];
    const float* up_vals[4];
    const float* enW[4];
    const float* enb[4];
    for (int l = 0; l < 4; ++l) {
        int base = 1 + 9 * l;
        sp[l]      = (const int*)d_in[base + 0];
        dn_cols[l] = (const int*)d_in[base + 2];
        dn_vals[l] = (const float*)d_in[base + 3];
        up_cols[l] = (const int*)d_in[base + 5];
        up_vals[l] = (const float*)d_in[base + 6];
        enW[l]     = (const float*)d_in[base + 7];
        enb[l]     = (const float*)d_in[base + 8];
    }
    const float* muW  = (const float*)d_in[37];
    const float* mub  = (const float*)d_in[38];
    const float* deW0 = (const float*)d_in[39];
    const float* deb0 = (const float*)d_in[40];
    const float* dW[4]  = { (const float*)d_in[41], (const float*)d_in[43],
                            (const float*)d_in[45], (const float*)d_in[47] };
    const float* db[4]  = { (const float*)d_in[42], (const float*)d_in[44],
                            (const float*)d_in[46], (const float*)d_in[48] };
    const float* outW = (const float*)d_in[49];
    const float* outb = (const float*)d_in[50];

    // ws layout (bytes): A bf16 [0, 51.2M), B bf16 [51.2M, 153.6M), Z f32 small
    char* ws = (char*)d_ws;
    bf16*  A  = (bf16*)ws;                       // cap 25,600,000 bf16
    bf16*  Bb = (bf16*)(ws + 51200000);          // cap 51,200,000 bf16
    float* Z  = (float*)(ws + 153600000);        // 4096 f32
    float* outF   = (float*)d_out;
    float* out_z  = outF + 4800000;
    float* out_mu = outF + 4804096;

    auto cdiv = [](int a, int b) { return (a + b - 1) / b; };
    auto pool = [&](const bf16* in, const int* cols, const float* vals,
                    bf16* out, int M, int Nin, int C) {
        int C8 = C / 8;
        int total = BATCH * M * C8;
        pool_kernel<<<cdiv(total, 256), 256, 0, stream>>>(in, cols, vals, out, M, Nin, C8);
    };

    // -------- encoder --------
    sconv_kernel<3, 16, 16, 16, 1, float, bf16><<<cdiv(BATCH * NS0, 16), 256, 0, stream>>>(x,  sp[0], enW[0], enb[0], A,  NS0);
    pool(A, dn_cols[0], dn_vals[0], Bb, NS1, NS0, 16);
    sconv_kernel<16, 32, 32, 8, 1, bf16, bf16><<<cdiv(BATCH * NS1, 8), 256, 0, stream>>>(Bb, sp[1], enW[1], enb[1], A,  NS1);
    pool(A, dn_cols[1], dn_vals[1], Bb, NS2, NS1, 32);
    sconv_kernel<32, 64, 64, 4, 1, bf16, bf16><<<cdiv(BATCH * NS2, 4), 256, 0, stream>>>(Bb, sp[2], enW[2], enb[2], A,  NS2);
    pool(A, dn_cols[2], dn_vals[2], Bb, NS3, NS2, 64);
    sconv_kernel<64, 128, 128, 2, 1, bf16, bf16><<<cdiv(BATCH * NS3, 2), 256, 0, stream>>>(Bb, sp[3], enW[3], enb[3], A, NS3);
    pool(A, dn_cols[3], dn_vals[3], Bb, NS4, NS3, 128);

    // -------- latent --------
    mu_kernel<<<BATCH, 128, 0, stream>>>(Bb, muW, mub, Z, out_z, out_mu);
    de0_kernel<<<25600 / 256, 256, 0, stream>>>(Z, deW0, deb0, A);   // A = (32,200,128)

    // -------- decoder --------
    pool(A, up_cols[3], up_vals[3], Bb, NS3, NS4, 128);
    sconv_kernel<128, 128, 128, 2, 1, bf16, bf16><<<cdiv(BATCH * NS3, 2), 256, 0, stream>>>(Bb, sp[3], dW[0], db[0], A, NS3);
    pool(A, up_cols[2], up_vals[2], Bb, NS2, NS3, 128);
    sconv_kernel<128, 64, 64, 4, 1, bf16, bf16><<<cdiv(BATCH * NS2, 4), 256, 0, stream>>>(Bb, sp[2], dW[1], db[1], A, NS2);
    pool(A, up_cols[1], up_vals[1], Bb, NS1, NS2, 64);
    sconv_kernel<64, 32, 32, 8, 1, bf16, bf16><<<cdiv(BATCH * NS1, 8), 256, 0, stream>>>(Bb, sp[1], dW[2], db[2], A, NS1);
    pool(A, up_cols[0], up_vals[0], Bb, NS0, NS1, 32);
    sconv_kernel<32, 16, 16, 16, 1, bf16, bf16><<<cdiv(BATCH * NS0, 16), 256, 0, stream>>>(Bb, sp[0], dW[3], db[3], A, NS0);

    // -------- output conv (no activation), straight into d_out (fp32) -------
    sconv_kernel<16, 3, 4, 64, 0, bf16, float><<<cdiv(BATCH * NS0, 64), 256, 0, stream>>>(A, sp[0], outW, outb, outF, NS0);
}

// Round 3
// 1997.864 us; speedup vs baseline: 3.4312x; 3.4312x over previous
//
#include <hip/hip_runtime.h>
#include <hip/hip_bf16.h>
#include <math.h>

#define NS0 50000
#define NS1 12500
#define NS2 3125
#define NS3 800
#define NS4 200
#define BATCH 32
#define SLEN 9

typedef __hip_bfloat16 bf16;
typedef __attribute__((ext_vector_type(8))) short short8_t;
typedef __attribute__((ext_vector_type(4))) float f32x4;

// ---------------- W conversion: fp32 (K,CO) row-major -> bf16 (COP,KP) cm ---
__global__ void __launch_bounds__(256)
wconv_kernel(const float* __restrict__ W, bf16* __restrict__ dst,
             int K, int CO, int KP, int COP)
{
    int i = blockIdx.x * 256 + threadIdx.x;
    int total = COP * KP;
    if (i >= total) return;
    int co = i / KP, k = i - co * KP;
    float v = (k < K && co < CO) ? W[k * CO + co] : 0.f;
    dst[i] = __float2bfloat16(v);
}

// ---------------- MFMA SpiralConv -------------------------------------------
// x: (B,NN,CIN) TIN ; idx: (NN,S) ; Wcm: (COP, KP) bf16 col-major ; bias fp32
// y: (B,NN,COUT) TOUT.  Block: NW waves, RPB rows staged in LDS (bf16).
// Wave w: col-block cb = w%NCB (16 cols), row-group rg = w/NCB.
template<int CIN, int COUT, int COP, int NW, int RPB, int ACT, int NN,
         typename TIN, typename TOUT>
__global__ void __launch_bounds__(NW * 64)
sconv_mfma(const TIN* __restrict__ x, const int* __restrict__ idx,
           const bf16* __restrict__ Wcm, const float* __restrict__ bias,
           TOUT* __restrict__ y)
{
    constexpr int KLEN = (CIN == 3) ? 27 : 9 * CIN;
    constexpr int KP   = (KLEN + 31) / 32 * 32;
    constexpr int ZPAD = KP - KLEN;
    constexpr int STRIDE = KP + 8;           // bf16 elems; keeps b128 reads conflict-free
    constexpr int NCB = COP / 16;
    constexpr int NRG = NW / NCB;
    constexpr int RPW = RPB / NRG;
    constexpr int NFRAG = RPW / 16;
    constexpr int NKK = KP / 32;

    __shared__ short lds[RPB * STRIDE];
    const int t = threadIdx.x;
    const int row0 = blockIdx.x * RPB;

    // zero the K-pad (so pad never contributes NaN via uninit LDS)
    if constexpr (ZPAD > 0) {
        for (int e = t; e < RPB * ZPAD; e += NW * 64) {
            int r = e / ZPAD, k = KLEN + (e - r * ZPAD);
            lds[r * STRIDE + k] = 0;
        }
    }
    // gather
    if constexpr (CIN == 3) {
        for (int e = t; e < RPB * SLEN; e += NW * 64) {
            int r = e / SLEN, s = e - r * SLEN;
            int g = row0 + r;
            int b = g / NN, n = g - b * NN;
            int j = idx[n * SLEN + s];
            const float* xb = (const float*)x + (size_t)(b * NN + j) * 3;
            short* dst = &lds[r * STRIDE + s * 3];
            dst[0] = __bfloat16_as_short(__float2bfloat16(xb[0]));
            dst[1] = __bfloat16_as_short(__float2bfloat16(xb[1]));
            dst[2] = __bfloat16_as_short(__float2bfloat16(xb[2]));
        }
    } else {
        constexpr int C16 = CIN / 8;           // 16B chunks per neighbor row
        for (int e = t; e < RPB * SLEN * C16; e += NW * 64) {
            int r = e / (SLEN * C16);
            int rem = e - r * (SLEN * C16);
            int s = rem / C16, c = rem - s * C16;
            int g = row0 + r;
            int b = g / NN, n = g - b * NN;
            int j = idx[n * SLEN + s];
            uint4 v = *(const uint4*)((const bf16*)x + (size_t)(b * NN + j) * CIN + c * 8);
            *(uint4*)&lds[r * STRIDE + s * CIN + c * 8] = v;
        }
    }
    __syncthreads();

    const int w = t >> 6, lane = t & 63;
    const int cb = w % NCB, rg = w / NCB;
    const int col = cb * 16 + (lane & 15);
    const int kh = lane >> 4;                  // 0..3
    const int rbase = rg * RPW;

    float bcol = (col < COUT) ? bias[col] : 0.f;
    f32x4 acc[NFRAG];
    #pragma unroll
    for (int f = 0; f < NFRAG; ++f) acc[f] = (f32x4){bcol, bcol, bcol, bcol};

    const bf16* wp = Wcm + (size_t)col * KP + kh * 8;
    #pragma unroll
    for (int kk = 0; kk < NKK; ++kk) {
        short8_t bfr = *(const short8_t*)(wp + kk * 32);
        #pragma unroll
        for (int f = 0; f < NFRAG; ++f) {
            short8_t afr = *(const short8_t*)&lds[(rbase + f * 16 + (lane & 15)) * STRIDE + kk * 32 + kh * 8];
            acc[f] = __builtin_amdgcn_mfma_f32_16x16x32_bf16(afr, bfr, acc[f], 0, 0, 0);
        }
    }

    if (col < COUT) {
        #pragma unroll
        for (int f = 0; f < NFRAG; ++f) {
            #pragma unroll
            for (int i = 0; i < 4; ++i) {
                int row = row0 + rbase + f * 16 + kh * 4 + i;
                float v = acc[f][i];
                if (ACT) v = v > 0.f ? v : expm1f(v);
                TOUT* dst = &y[(size_t)row * COUT + col];
                if constexpr (__is_same(TOUT, float)) *dst = v;
                else *dst = __float2bfloat16(v);
            }
        }
    }
}

// ---------------- Pool: structured K=4 segment sum, bf16 --------------------
__global__ void __launch_bounds__(256)
pool_kernel(const bf16* __restrict__ x, const int* __restrict__ cols,
            const float* __restrict__ vals, bf16* __restrict__ y,
            int M, int Nin, int C8)
{
    int tid = blockIdx.x * 256 + threadIdx.x;
    int total = BATCH * M * C8;
    if (tid >= total) return;
    int c8 = tid % C8;
    int bm = tid / C8;
    int m = bm % M;
    int b = bm / M;
    float acc[8];
    #pragma unroll
    for (int e = 0; e < 8; ++e) acc[e] = 0.f;
    #pragma unroll
    for (int j = 0; j < 4; ++j) {
        int col = cols[m * 4 + j];
        float v = vals[m * 4 + j];
        uint4 u = ((const uint4*)x)[(size_t)(b * Nin + col) * C8 + c8];
        const bf16* h = (const bf16*)&u;
        #pragma unroll
        for (int e = 0; e < 8; ++e)
            acc[e] = fmaf(v, __bfloat162float(h[e]), acc[e]);
    }
    uint4 o;
    bf16* oh = (bf16*)&o;
    #pragma unroll
    for (int e = 0; e < 8; ++e) oh[e] = __float2bfloat16(acc[e]);
    ((uint4*)y)[(size_t)(b * M + m) * C8 + c8] = o;
}

// ---------------- mu = sigmoid(h @ muW + mub) -------------------------------
__global__ void __launch_bounds__(128)
mu_kernel(const bf16* __restrict__ h, const float* __restrict__ W,
          const float* __restrict__ bias, float* __restrict__ z,
          float* __restrict__ out_z, float* __restrict__ out_mu)
{
    __shared__ float hs[128];
    const int b = blockIdx.x;
    const int co = threadIdx.x;
    const bf16* hb = h + b * 25600;
    float acc = bias[co];
    for (int k0 = 0; k0 < 25600; k0 += 128) {
        __syncthreads();
        hs[co] = __bfloat162float(hb[k0 + co]);
        __syncthreads();
        #pragma unroll 8
        for (int kk = 0; kk < 128; ++kk)
            acc = fmaf(hs[kk], W[(k0 + kk) * 128 + co], acc);
    }
    float m = 1.f / (1.f + expf(-acc));
    z[b * 128 + co] = m;
    out_z[b * 128 + co] = m;
    out_mu[b * 128 + co] = m;
}

// ---------------- d0 = z @ deW0 + deb0 --------------------------------------
__global__ void __launch_bounds__(256)
de0_kernel(const float* __restrict__ z, const float* __restrict__ W,
           const float* __restrict__ bias, bf16* __restrict__ d)
{
    __shared__ float zs[BATCH * 128];
    const int t = threadIdx.x;
    for (int e = t; e < BATCH * 128; e += 256) zs[e] = z[e];
    __syncthreads();
    const int j = blockIdx.x * 256 + t;
    float bj = bias[j];
    float acc[BATCH];
    #pragma unroll
    for (int b = 0; b < BATCH; ++b) acc[b] = bj;
    for (int k = 0; k < 128; ++k) {
        float w = W[k * 25600 + j];
        #pragma unroll
        for (int b = 0; b < BATCH; ++b)
            acc[b] = fmaf(zs[b * 128 + k], w, acc[b]);
    }
    #pragma unroll
    for (int b = 0; b < BATCH; ++b)
        d[b * 25600 + j] = __float2bfloat16(acc[b]);
}

extern "C" void kernel_launch(void* const* d_in, const int* in_sizes, int n_in,
                              void* d_out, int out_size, void* d_ws, size_t ws_size,
                              hipStream_t stream)
{
    const float* x = (const float*)d_in[0];
    const int*   sp[4];
    const int*   dn_cols[4];
    const float* dn_vals[4];
    const int*   up_cols[4];
    const float* up_vals[4];
    const float* enW[4];
    const float* enb[4];
    for (int l = 0; l < 4; ++l) {
        int base = 1 + 9 * l;
        sp[l]      = (const int*)d_in[base + 0];
        dn_cols[l] = (const int*)d_in[base + 2];
        dn_vals[l] = (const float*)d_in[base + 3];
        up_cols[l] = (const int*)d_in[base + 5];
        up_vals[l] = (const float*)d_in[base + 6];
        enW[l]     = (const float*)d_in[base + 7];
        enb[l]     = (const float*)d_in[base + 8];
    }
    const float* muW  = (const float*)d_in[37];
    const float* mub  = (const float*)d_in[38];
    const float* deW0 = (const float*)d_in[39];
    const float* deb0 = (const float*)d_in[40];
    const float* dW[4]  = { (const float*)d_in[41], (const float*)d_in[43],
                            (const float*)d_in[45], (const float*)d_in[47] };
    const float* db[4]  = { (const float*)d_in[42], (const float*)d_in[44],
                            (const float*)d_in[46], (const float*)d_in[48] };
    const float* outW = (const float*)d_in[49];
    const float* outb = (const float*)d_in[50];

    // ws: A bf16 [0,51.2MB), B bf16 [51.2,153.6MB), Z f32, small Wcm
    char* ws = (char*)d_ws;
    bf16*  A  = (bf16*)ws;
    bf16*  Bb = (bf16*)(ws + 51200000);
    float* Z  = (float*)(ws + 153600000);
    bf16*  wEN0 = (bf16*)(ws + 153600000 + 16384);   // 512
    bf16*  wOUT = wEN0 + 512;                        // 2560

    float* outF   = (float*)d_out;
    float* out_z  = outF + 4800000;
    float* out_mu = outF + 4804096;

    // big Wcm tables live in the (not-yet-written) d_out conv region as scratch
    bf16* wsc  = (bf16*)d_out;
    bf16* wEN1 = wsc;            // 32*160   = 5120
    bf16* wEN2 = wsc + 5120;     // 64*288   = 18432
    bf16* wEN3 = wsc + 23552;    // 128*576  = 73728
    bf16* wDW0 = wsc + 97280;    // 128*1152 = 147456
    bf16* wDW1 = wsc + 244736;   // 64*1152  = 73728
    bf16* wDW2 = wsc + 318464;   // 32*576   = 18432
    bf16* wDW3 = wsc + 336896;   // 16*288   = 4608   (total 341504 bf16 = 683KB)

    auto cdiv = [](int a, int b) { return (a + b - 1) / b; };
    auto wcv = [&](const float* W, bf16* dst, int K, int CO, int KP, int COP) {
        wconv_kernel<<<cdiv(COP * KP, 256), 256, 0, stream>>>(W, dst, K, CO, KP, COP);
    };
    wcv(enW[0], wEN0, 27, 16, 32, 16);
    wcv(enW[1], wEN1, 144, 32, 160, 32);
    wcv(enW[2], wEN2, 288, 64, 288, 64);
    wcv(enW[3], wEN3, 576, 128, 576, 128);
    wcv(dW[0], wDW0, 1152, 128, 1152, 128);
    wcv(dW[1], wDW1, 1152, 64, 1152, 64);
    wcv(dW[2], wDW2, 576, 32, 576, 32);
    wcv(dW[3], wDW3, 288, 16, 288, 16);
    wcv(outW, wOUT, 144, 3, 160, 16);

    auto pool = [&](const bf16* in, const int* cols, const float* vals,
                    bf16* out, int M, int Nin, int C) {
        int C8 = C / 8;
        int total = BATCH * M * C8;
        pool_kernel<<<cdiv(total, 256), 256, 0, stream>>>(in, cols, vals, out, M, Nin, C8);
    };

    // -------- encoder --------
    sconv_mfma<3, 16, 16, 4, 64, 1, NS0, float, bf16><<<BATCH * NS0 / 64, 256, 0, stream>>>(x, sp[0], wEN0, enb[0], A);
    pool(A, dn_cols[0], dn_vals[0], Bb, NS1, NS0, 16);
    sconv_mfma<16, 32, 32, 4, 64, 1, NS1, bf16, bf16><<<BATCH * NS1 / 64, 256, 0, stream>>>(Bb, sp[1], wEN1, enb[1], A);
    pool(A, dn_cols[1], dn_vals[1], Bb, NS2, NS1, 32);
    sconv_mfma<32, 64, 64, 4, 32, 1, NS2, bf16, bf16><<<BATCH * NS2 / 32, 256, 0, stream>>>(Bb, sp[2], wEN2, enb[2], A);
    pool(A, dn_cols[2], dn_vals[2], Bb, NS3, NS2, 64);
    sconv_mfma<64, 128, 128, 8, 32, 1, NS3, bf16, bf16><<<BATCH * NS3 / 32, 512, 0, stream>>>(Bb, sp[3], wEN3, enb[3], A);
    pool(A, dn_cols[3], dn_vals[3], Bb, NS4, NS3, 128);

    // -------- latent --------
    mu_kernel<<<BATCH, 128, 0, stream>>>(Bb, muW, mub, Z, out_z, out_mu);
    de0_kernel<<<25600 / 256, 256, 0, stream>>>(Z, deW0, deb0, A);

    // -------- decoder --------
    pool(A, up_cols[3], up_vals[3], Bb, NS3, NS4, 128);
    sconv_mfma<128, 128, 128, 8, 16, 1, NS3, bf16, bf16><<<BATCH * NS3 / 16, 512, 0, stream>>>(Bb, sp[3], wDW0, db[0], A);
    pool(A, up_cols[2], up_vals[2], Bb, NS2, NS3, 128);
    sconv_mfma<128, 64, 64, 4, 16, 1, NS2, bf16, bf16><<<BATCH * NS2 / 16, 256, 0, stream>>>(Bb, sp[2], wDW1, db[1], A);
    pool(A, up_cols[1], up_vals[1], Bb, NS1, NS2, 64);
    sconv_mfma<64, 32, 32, 4, 32, 1, NS1, bf16, bf16><<<BATCH * NS1 / 32, 256, 0, stream>>>(Bb, sp[1], wDW2, db[2], A);
    pool(A, up_cols[0], up_vals[0], Bb, NS0, NS1, 32);
    sconv_mfma<32, 16, 16, 4, 64, 1, NS0, bf16, bf16><<<BATCH * NS0 / 64, 256, 0, stream>>>(Bb, sp[0], wDW3, db[3], A);

    // -------- output conv (fp32 into d_out; overwrites the Wcm scratch) -----
    sconv_mfma<16, 3, 16, 4, 64, 0, NS0, bf16, float><<<BATCH * NS0 / 64, 256, 0, stream>>>(A, sp[0], wOUT, outb, outF);
}

// Round 4
// 1097.741 us; speedup vs baseline: 6.2447x; 1.8200x over previous
//
#include <hip/hip_runtime.h>
#include <hip/hip_bf16.h>
#include <math.h>

#define NS0 50000
#define NS1 12500
#define NS2 3125
#define NS3 800
#define NS4 200
#define BATCH 32
#define SLEN 9

typedef __hip_bfloat16 bf16;
typedef __attribute__((ext_vector_type(8))) short short8_t;
typedef __attribute__((ext_vector_type(4))) float f32x4;

// ---------------- fused W conversion: 9 segments, fp32 (K,CO) -> bf16 cm ----
struct WcvAll {
    const float* W[9];
    bf16* dst[9];
    int K[9], CO[9], KP[9];
    int off[10];   // cumulative element offsets (elements = COP*KP)
};

__global__ void __launch_bounds__(256)
wconv_all_kernel(WcvAll p)
{
    int gid = blockIdx.x * 256 + threadIdx.x;
    if (gid >= p.off[9]) return;
    int seg = 0;
    #pragma unroll
    for (int s = 1; s < 9; ++s) seg += (gid >= p.off[s]);
    int local = gid - p.off[seg];
    int KP = p.KP[seg];
    int co = local / KP, k = local - co * KP;
    float v = (k < p.K[seg] && co < p.CO[seg]) ? p.W[seg][k * p.CO[seg] + co] : 0.f;
    p.dst[seg][local] = __float2bfloat16(v);
}

// ---------------- MFMA SpiralConv -------------------------------------------
template<int CIN, int COUT, int COP, int NW, int RPB, int ACT, int NN,
         typename TIN, typename TOUT>
__global__ void __launch_bounds__(NW * 64)
sconv_mfma(const TIN* __restrict__ x, const int* __restrict__ idx,
           const bf16* __restrict__ Wcm, const float* __restrict__ bias,
           TOUT* __restrict__ y)
{
    constexpr int KLEN = (CIN == 3) ? 27 : 9 * CIN;
    constexpr int KP   = (KLEN + 31) / 32 * 32;
    constexpr int ZPAD = KP - KLEN;
    constexpr int STRIDE = KP + 8;
    constexpr int NCB = COP / 16;
    constexpr int NRG = NW / NCB;
    constexpr int RPW = RPB / NRG;
    constexpr int NFRAG = RPW / 16;
    constexpr int NKK = KP / 32;

    __shared__ short lds[RPB * STRIDE];
    const int t = threadIdx.x;
    const int row0 = blockIdx.x * RPB;

    if constexpr (ZPAD > 0) {
        for (int e = t; e < RPB * ZPAD; e += NW * 64) {
            int r = e / ZPAD, k = KLEN + (e - r * ZPAD);
            lds[r * STRIDE + k] = 0;
        }
    }
    if constexpr (CIN == 3) {
        for (int e = t; e < RPB * SLEN; e += NW * 64) {
            int r = e / SLEN, s = e - r * SLEN;
            int g = row0 + r;
            int b = g / NN, n = g - b * NN;
            int j = idx[n * SLEN + s];
            const float* xb = (const float*)x + (size_t)(b * NN + j) * 3;
            short* dst = &lds[r * STRIDE + s * 3];
            dst[0] = __bfloat16_as_short(__float2bfloat16(xb[0]));
            dst[1] = __bfloat16_as_short(__float2bfloat16(xb[1]));
            dst[2] = __bfloat16_as_short(__float2bfloat16(xb[2]));
        }
    } else {
        constexpr int C16 = CIN / 8;
        for (int e = t; e < RPB * SLEN * C16; e += NW * 64) {
            int r = e / (SLEN * C16);
            int rem = e - r * (SLEN * C16);
            int s = rem / C16, c = rem - s * C16;
            int g = row0 + r;
            int b = g / NN, n = g - b * NN;
            int j = idx[n * SLEN + s];
            uint4 v = *(const uint4*)((const bf16*)x + (size_t)(b * NN + j) * CIN + c * 8);
            *(uint4*)&lds[r * STRIDE + s * CIN + c * 8] = v;
        }
    }
    __syncthreads();

    const int w = t >> 6, lane = t & 63;
    const int cb = w % NCB, rg = w / NCB;
    const int col = cb * 16 + (lane & 15);
    const int kh = lane >> 4;
    const int rbase = rg * RPW;

    float bcol = (col < COUT) ? bias[col] : 0.f;
    f32x4 acc[NFRAG];
    #pragma unroll
    for (int f = 0; f < NFRAG; ++f) acc[f] = (f32x4){bcol, bcol, bcol, bcol};

    const bf16* wp = Wcm + (size_t)col * KP + kh * 8;
    #pragma unroll
    for (int kk = 0; kk < NKK; ++kk) {
        short8_t bfr = *(const short8_t*)(wp + kk * 32);
        #pragma unroll
        for (int f = 0; f < NFRAG; ++f) {
            short8_t afr = *(const short8_t*)&lds[(rbase + f * 16 + (lane & 15)) * STRIDE + kk * 32 + kh * 8];
            acc[f] = __builtin_amdgcn_mfma_f32_16x16x32_bf16(afr, bfr, acc[f], 0, 0, 0);
        }
    }

    if (col < COUT) {
        #pragma unroll
        for (int f = 0; f < NFRAG; ++f) {
            #pragma unroll
            for (int i = 0; i < 4; ++i) {
                int row = row0 + rbase + f * 16 + kh * 4 + i;
                float v = acc[f][i];
                if (ACT) v = v > 0.f ? v : expm1f(v);
                TOUT* dst = &y[(size_t)row * COUT + col];
                if constexpr (__is_same(TOUT, float)) *dst = v;
                else *dst = __float2bfloat16(v);
            }
        }
    }
}

// ---------------- Pool: structured K=4 segment sum, bf16 --------------------
__global__ void __launch_bounds__(256)
pool_kernel(const bf16* __restrict__ x, const int* __restrict__ cols,
            const float* __restrict__ vals, bf16* __restrict__ y,
            int M, int Nin, int C8)
{
    int tid = blockIdx.x * 256 + threadIdx.x;
    int total = BATCH * M * C8;
    if (tid >= total) return;
    int c8 = tid % C8;
    int bm = tid / C8;
    int m = bm % M;
    int b = bm / M;
    float acc[8];
    #pragma unroll
    for (int e = 0; e < 8; ++e) acc[e] = 0.f;
    #pragma unroll
    for (int j = 0; j < 4; ++j) {
        int col = cols[m * 4 + j];
        float v = vals[m * 4 + j];
        uint4 u = ((const uint4*)x)[(size_t)(b * Nin + col) * C8 + c8];
        const bf16* h = (const bf16*)&u;
        #pragma unroll
        for (int e = 0; e < 8; ++e)
            acc[e] = fmaf(v, __bfloat162float(h[e]), acc[e]);
    }
    uint4 o;
    bf16* oh = (bf16*)&o;
    #pragma unroll
    for (int e = 0; e < 8; ++e) oh[e] = __float2bfloat16(acc[e]);
    ((uint4*)y)[(size_t)(b * M + m) * C8 + c8] = o;
}

// ---------------- mu split-K: partial[c] = h[:,c*128:(c+1)*128] @ W[slice] --
// h: (32, 25600) bf16 ; W: (25600, 128) fp32 ; partial: (200, 32, 128) fp32
__global__ void __launch_bounds__(256)
mu_partial_kernel(const bf16* __restrict__ h, const float* __restrict__ W,
                  float* __restrict__ partial)
{
    __shared__ float hs[BATCH * 128];
    const int t = threadIdx.x;
    const int k0 = blockIdx.x * 128;
    for (int e = t; e < BATCH * 128; e += 256) {
        int b = e >> 7, k = e & 127;
        hs[e] = __bfloat162float(h[b * 25600 + k0 + k]);
    }
    __syncthreads();
    const int co = t & 127;
    const int bh = t >> 7;           // 0 or 1 -> batches [bh*16, bh*16+16)
    float acc[16];
    #pragma unroll
    for (int i = 0; i < 16; ++i) acc[i] = 0.f;
    for (int k = 0; k < 128; ++k) {
        float w = W[(size_t)(k0 + k) * 128 + co];
        #pragma unroll
        for (int i = 0; i < 16; ++i)
            acc[i] = fmaf(hs[(bh * 16 + i) * 128 + k], w, acc[i]);
    }
    float* pb = partial + (size_t)blockIdx.x * 4096;
    #pragma unroll
    for (int i = 0; i < 16; ++i)
        pb[(bh * 16 + i) * 128 + co] = acc[i];
}

// ---------------- mu reduce: sum 200 partials + bias -> sigmoid -------------
__global__ void __launch_bounds__(256)
mu_reduce_kernel(const float* __restrict__ partial, const float* __restrict__ bias,
                 float* __restrict__ z, float* __restrict__ out_z,
                 float* __restrict__ out_mu)
{
    const int i = blockIdx.x * 256 + threadIdx.x;   // 0..4095
    const int co = i & 127;
    float a0 = 0.f, a1 = 0.f, a2 = 0.f, a3 = 0.f;
    #pragma unroll 4
    for (int c = 0; c < 200; c += 4) {
        a0 += partial[(size_t)c * 4096 + i];
        a1 += partial[(size_t)(c + 1) * 4096 + i];
        a2 += partial[(size_t)(c + 2) * 4096 + i];
        a3 += partial[(size_t)(c + 3) * 4096 + i];
    }
    float acc = (a0 + a1) + (a2 + a3) + bias[co];
    float m = 1.f / (1.f + expf(-acc));
    z[i] = m;
    out_z[i] = m;
    out_mu[i] = m;
}

// ---------------- d0 = z @ deW0 + deb0 --------------------------------------
__global__ void __launch_bounds__(256)
de0_kernel(const float* __restrict__ z, const float* __restrict__ W,
           const float* __restrict__ bias, bf16* __restrict__ d)
{
    __shared__ float zs[BATCH * 128];
    const int t = threadIdx.x;
    for (int e = t; e < BATCH * 128; e += 256) zs[e] = z[e];
    __syncthreads();
    const int j = blockIdx.x * 256 + t;
    float bj = bias[j];
    float acc[BATCH];
    #pragma unroll
    for (int b = 0; b < BATCH; ++b) acc[b] = bj;
    for (int k = 0; k < 128; ++k) {
        float w = W[k * 25600 + j];
        #pragma unroll
        for (int b = 0; b < BATCH; ++b)
            acc[b] = fmaf(zs[b * 128 + k], w, acc[b]);
    }
    #pragma unroll
    for (int b = 0; b < BATCH; ++b)
        d[b * 25600 + j] = __float2bfloat16(acc[b]);
}

extern "C" void kernel_launch(void* const* d_in, const int* in_sizes, int n_in,
                              void* d_out, int out_size, void* d_ws, size_t ws_size,
                              hipStream_t stream)
{
    const float* x = (const float*)d_in[0];
    const int*   sp[4];
    const int*   dn_cols[4];
    const float* dn_vals[4];
    const int*   up_cols[4];
    const float* up_vals[4];
    const float* enW[4];
    const float* enb[4];
    for (int l = 0; l < 4; ++l) {
        int base = 1 + 9 * l;
        sp[l]      = (const int*)d_in[base + 0];
        dn_cols[l] = (const int*)d_in[base + 2];
        dn_vals[l] = (const float*)d_in[base + 3];
        up_cols[l] = (const int*)d_in[base + 5];
        up_vals[l] = (const float*)d_in[base + 6];
        enW[l]     = (const float*)d_in[base + 7];
        enb[l]     = (const float*)d_in[base + 8];
    }
    const float* muW  = (const float*)d_in[37];
    const float* mub  = (const float*)d_in[38];
    const float* deW0 = (const float*)d_in[39];
    const float* deb0 = (const float*)d_in[40];
    const float* dW[4]  = { (const float*)d_in[41], (const float*)d_in[43],
                            (const float*)d_in[45], (const float*)d_in[47] };
    const float* db[4]  = { (const float*)d_in[42], (const float*)d_in[44],
                            (const float*)d_in[46], (const float*)d_in[48] };
    const float* outW = (const float*)d_in[49];
    const float* outb = (const float*)d_in[50];

    // ws: A bf16 [0,51.2MB), B bf16 [51.2,153.6MB), Z f32 + small Wcm after
    char* ws = (char*)d_ws;
    bf16*  A  = (bf16*)ws;
    bf16*  Bb = (bf16*)(ws + 51200000);
    float* Z  = (float*)(ws + 153600000);
    bf16*  wEN0 = (bf16*)(ws + 153600000 + 16384);
    bf16*  wOUT = wEN0 + 512;

    float* outF   = (float*)d_out;
    float* out_z  = outF + 4800000;
    float* out_mu = outF + 4804096;

    // scratch inside d_out's conv region (overwritten by the final conv):
    bf16*  wsc  = (bf16*)d_out;          // Wcm tables: [0, 341504) bf16
    bf16*  wEN1 = wsc;
    bf16*  wEN2 = wsc + 5120;
    bf16*  wEN3 = wsc + 23552;
    bf16*  wDW0 = wsc + 97280;
    bf16*  wDW1 = wsc + 244736;
    bf16*  wDW2 = wsc + 318464;
    bf16*  wDW3 = wsc + 336896;
    float* muPart = outF + 1000000;      // [1.0M, 1.82M) floats: 200*4096 f32

    // fused weight conversion (9 segments, 1 launch)
    WcvAll wp;
    const float* srcs[9] = {enW[0], enW[1], enW[2], enW[3], dW[0], dW[1], dW[2], dW[3], outW};
    bf16* dsts[9] = {wEN0, wEN1, wEN2, wEN3, wDW0, wDW1, wDW2, wDW3, wOUT};
    int Ks[9]  = {27, 144, 288, 576, 1152, 1152, 576, 288, 144};
    int COs[9] = {16, 32, 64, 128, 128, 64, 32, 16, 3};
    int KPs[9] = {32, 160, 288, 576, 1152, 1152, 576, 288, 160};
    int COPs[9] = {16, 32, 64, 128, 128, 64, 32, 16, 16};
    int off = 0;
    for (int s = 0; s < 9; ++s) {
        wp.W[s] = srcs[s]; wp.dst[s] = dsts[s];
        wp.K[s] = Ks[s]; wp.CO[s] = COs[s]; wp.KP[s] = KPs[s];
        wp.off[s] = off; off += COPs[s] * KPs[s];
    }
    wp.off[9] = off;
    auto cdiv = [](int a, int b) { return (a + b - 1) / b; };
    wconv_all_kernel<<<cdiv(off, 256), 256, 0, stream>>>(wp);

    auto pool = [&](const bf16* in, const int* cols, const float* vals,
                    bf16* out, int M, int Nin, int C) {
        int C8 = C / 8;
        int total = BATCH * M * C8;
        pool_kernel<<<cdiv(total, 256), 256, 0, stream>>>(in, cols, vals, out, M, Nin, C8);
    };

    // -------- encoder --------
    sconv_mfma<3, 16, 16, 4, 64, 1, NS0, float, bf16><<<BATCH * NS0 / 64, 256, 0, stream>>>(x, sp[0], wEN0, enb[0], A);
    pool(A, dn_cols[0], dn_vals[0], Bb, NS1, NS0, 16);
    sconv_mfma<16, 32, 32, 4, 64, 1, NS1, bf16, bf16><<<BATCH * NS1 / 64, 256, 0, stream>>>(Bb, sp[1], wEN1, enb[1], A);
    pool(A, dn_cols[1], dn_vals[1], Bb, NS2, NS1, 32);
    sconv_mfma<32, 64, 64, 4, 32, 1, NS2, bf16, bf16><<<BATCH * NS2 / 32, 256, 0, stream>>>(Bb, sp[2], wEN2, enb[2], A);
    pool(A, dn_cols[2], dn_vals[2], Bb, NS3, NS2, 64);
    sconv_mfma<64, 128, 128, 8, 32, 1, NS3, bf16, bf16><<<BATCH * NS3 / 32, 512, 0, stream>>>(Bb, sp[3], wEN3, enb[3], A);
    pool(A, dn_cols[3], dn_vals[3], Bb, NS4, NS3, 128);

    // -------- latent (split-K mu, then de0) --------
    mu_partial_kernel<<<200, 256, 0, stream>>>(Bb, muW, muPart);
    mu_reduce_kernel<<<16, 256, 0, stream>>>(muPart, mub, Z, out_z, out_mu);
    de0_kernel<<<25600 / 256, 256, 0, stream>>>(Z, deW0, deb0, A);

    // -------- decoder --------
    pool(A, up_cols[3], up_vals[3], Bb, NS3, NS4, 128);
    sconv_mfma<128, 128, 128, 8, 16, 1, NS3, bf16, bf16><<<BATCH * NS3 / 16, 512, 0, stream>>>(Bb, sp[3], wDW0, db[0], A);
    pool(A, up_cols[2], up_vals[2], Bb, NS2, NS3, 128);
    sconv_mfma<128, 64, 64, 4, 16, 1, NS2, bf16, bf16><<<BATCH * NS2 / 16, 256, 0, stream>>>(Bb, sp[2], wDW1, db[1], A);
    pool(A, up_cols[1], up_vals[1], Bb, NS1, NS2, 64);
    sconv_mfma<64, 32, 32, 4, 32, 1, NS1, bf16, bf16><<<BATCH * NS1 / 32, 256, 0, stream>>>(Bb, sp[1], wDW2, db[2], A);
    pool(A, up_cols[0], up_vals[0], Bb, NS0, NS1, 32);
    sconv_mfma<32, 16, 16, 4, 64, 1, NS0, bf16, bf16><<<BATCH * NS0 / 64, 256, 0, stream>>>(Bb, sp[0], wDW3, db[3], A);

    // -------- output conv (fp32 into d_out; overwrites scratch) -------------
    sconv_mfma<16, 3, 16, 4, 64, 0, NS0, bf16, float><<<BATCH * NS0 / 64, 256, 0, stream>>>(A, sp[0], wOUT, outb, outF);
}

// Round 5
// 996.862 us; speedup vs baseline: 6.8767x; 1.1012x over previous
//
#include <hip/hip_runtime.h>
#include <hip/hip_bf16.h>
#include <math.h>

#define NS0 50000
#define NS1 12500
#define NS2 3125
#define NS3 800
#define NS4 200
#define BATCH 32
#define SLEN 9

typedef __hip_bfloat16 bf16;
typedef __attribute__((ext_vector_type(8))) short short8_t;
typedef __attribute__((ext_vector_type(4))) float f32x4;

// ---------------- fused W conversion: 9 segments, fp32 (K,CO) -> bf16 cm ----
struct WcvAll {
    const float* W[9];
    bf16* dst[9];
    int K[9], CO[9], KP[9];
    int off[10];
};

__global__ void __launch_bounds__(256)
wconv_all_kernel(WcvAll p)
{
    int gid = blockIdx.x * 256 + threadIdx.x;
    if (gid >= p.off[9]) return;
    int seg = 0;
    #pragma unroll
    for (int s = 1; s < 9; ++s) seg += (gid >= p.off[s]);
    int local = gid - p.off[seg];
    int KP = p.KP[seg];
    int co = local / KP, k = local - co * KP;
    float v = (k < p.K[seg] && co < p.CO[seg]) ? p.W[seg][k * p.CO[seg] + co] : 0.f;
    p.dst[seg][local] = __float2bfloat16(v);
}

// ---------------- LDS-staged MFMA SpiralConv (small-N / CIN=3 layers) -------
template<int CIN, int COUT, int COP, int NW, int RPB, int ACT, int NN,
         typename TIN, typename TOUT>
__global__ void __launch_bounds__(NW * 64)
sconv_mfma(const TIN* __restrict__ x, const int* __restrict__ idx,
           const bf16* __restrict__ Wcm, const float* __restrict__ bias,
           TOUT* __restrict__ y)
{
    constexpr int KLEN = (CIN == 3) ? 27 : 9 * CIN;
    constexpr int KP   = (KLEN + 31) / 32 * 32;
    constexpr int ZPAD = KP - KLEN;
    constexpr int STRIDE = KP + 8;
    constexpr int NCB = COP / 16;
    constexpr int NRG = NW / NCB;
    constexpr int RPW = RPB / NRG;
    constexpr int NFRAG = RPW / 16;
    constexpr int NKK = KP / 32;

    __shared__ short lds[RPB * STRIDE];
    const int t = threadIdx.x;
    const int row0 = blockIdx.x * RPB;

    if constexpr (ZPAD > 0) {
        for (int e = t; e < RPB * ZPAD; e += NW * 64) {
            int r = e / ZPAD, k = KLEN + (e - r * ZPAD);
            lds[r * STRIDE + k] = 0;
        }
    }
    if constexpr (CIN == 3) {
        for (int e = t; e < RPB * SLEN; e += NW * 64) {
            int r = e / SLEN, s = e - r * SLEN;
            int g = row0 + r;
            int b = g / NN, n = g - b * NN;
            int j = idx[n * SLEN + s];
            const float* xb = (const float*)x + (size_t)(b * NN + j) * 3;
            short* dst = &lds[r * STRIDE + s * 3];
            dst[0] = __bfloat16_as_short(__float2bfloat16(xb[0]));
            dst[1] = __bfloat16_as_short(__float2bfloat16(xb[1]));
            dst[2] = __bfloat16_as_short(__float2bfloat16(xb[2]));
        }
    } else {
        constexpr int C16 = CIN / 8;
        for (int e = t; e < RPB * SLEN * C16; e += NW * 64) {
            int r = e / (SLEN * C16);
            int rem = e - r * (SLEN * C16);
            int s = rem / C16, c = rem - s * C16;
            int g = row0 + r;
            int b = g / NN, n = g - b * NN;
            int j = idx[n * SLEN + s];
            uint4 v = *(const uint4*)((const bf16*)x + (size_t)(b * NN + j) * CIN + c * 8);
            *(uint4*)&lds[r * STRIDE + s * CIN + c * 8] = v;
        }
    }
    __syncthreads();

    const int w = t >> 6, lane = t & 63;
    const int cb = w % NCB, rg = w / NCB;
    const int col = cb * 16 + (lane & 15);
    const int kh = lane >> 4;
    const int rbase = rg * RPW;

    float bcol = (col < COUT) ? bias[col] : 0.f;
    f32x4 acc[NFRAG];
    #pragma unroll
    for (int f = 0; f < NFRAG; ++f) acc[f] = (f32x4){bcol, bcol, bcol, bcol};

    const bf16* wp = Wcm + (size_t)col * KP + kh * 8;
    #pragma unroll
    for (int kk = 0; kk < NKK; ++kk) {
        short8_t bfr = *(const short8_t*)(wp + kk * 32);
        #pragma unroll
        for (int f = 0; f < NFRAG; ++f) {
            short8_t afr = *(const short8_t*)&lds[(rbase + f * 16 + (lane & 15)) * STRIDE + kk * 32 + kh * 8];
            acc[f] = __builtin_amdgcn_mfma_f32_16x16x32_bf16(afr, bfr, acc[f], 0, 0, 0);
        }
    }

    if (col < COUT) {
        #pragma unroll
        for (int f = 0; f < NFRAG; ++f) {
            #pragma unroll
            for (int i = 0; i < 4; ++i) {
                int row = row0 + rbase + f * 16 + kh * 4 + i;
                float v = acc[f][i];
                if (ACT) v = v > 0.f ? v : expm1f(v);
                TOUT* dst = &y[(size_t)row * COUT + col];
                if constexpr (__is_same(TOUT, float)) *dst = v;
                else *dst = __float2bfloat16(v);
            }
        }
    }
}

// ---------------- direct MFMA SpiralConv: no LDS, fragment-aligned gather ---
// CIN in {16,32,64,128}. Wave handles 16 rows x COP cols.
// A-frag: row = lane&15, k = kk*32 + kh*8 + j  ->  neighbor s, channel ch.
template<int CIN, int COUT, int COP, int NW, int ACT, int NN, typename TOUT>
__global__ void __launch_bounds__(NW * 64)
sconv_direct(const bf16* __restrict__ x, const int* __restrict__ idx,
             const bf16* __restrict__ Wcm, const float* __restrict__ bias,
             TOUT* __restrict__ y)
{
    constexpr int KLEN = 9 * CIN;
    constexpr int KP   = (KLEN + 31) / 32 * 32;
    constexpr int NKK  = KP / 32;
    constexpr int NCB  = COP / 16;

    const int t = threadIdx.x;
    const int w = t >> 6, lane = t & 63;
    const int c = lane & 15, kh = lane >> 4;
    const int rowbase = blockIdx.x * (NW * 16) + w * 16;
    const int g = rowbase + c;                  // this lane's A-row
    const int b = g / NN, n = g - b * NN;

    // preload spiral indices (static-indexed; only used when CIN>=32)
    int jn[9];
    if constexpr (CIN >= 32) {
        #pragma unroll
        for (int s = 0; s < 9; ++s) jn[s] = idx[n * SLEN + s];
    }

    const int col0 = c;
    f32x4 acc[NCB];
    #pragma unroll
    for (int cb = 0; cb < NCB; ++cb) {
        int col = cb * 16 + col0;
        float bv = (col < COUT) ? bias[col] : 0.f;
        acc[cb] = (f32x4){bv, bv, bv, bv};
    }

    const size_t xrowbase = (size_t)b * NN;
    #pragma unroll
    for (int kk = 0; kk < NKK; ++kk) {
        short8_t afr;
        if constexpr (CIN == 16) {
            int s = 2 * kk + (kh >> 1);
            int ch = (kh & 1) * 8;
            if (s < 9) {
                int j = idx[n * SLEN + s];
                afr = *(const short8_t*)(x + (xrowbase + j) * CIN + ch);
            } else {
                afr = (short8_t){0, 0, 0, 0, 0, 0, 0, 0};
            }
        } else if constexpr (CIN == 32) {
            int j = jn[kk];
            afr = *(const short8_t*)(x + (xrowbase + j) * CIN + kh * 8);
        } else if constexpr (CIN == 64) {
            int j = jn[kk >> 1];
            afr = *(const short8_t*)(x + (xrowbase + j) * CIN + (kk & 1) * 32 + kh * 8);
        } else {   // 128
            int j = jn[kk >> 2];
            afr = *(const short8_t*)(x + (xrowbase + j) * CIN + (kk & 3) * 32 + kh * 8);
        }
        #pragma unroll
        for (int cb = 0; cb < NCB; ++cb) {
            short8_t bfr = *(const short8_t*)(Wcm + (size_t)(cb * 16 + col0) * KP + kk * 32 + kh * 8);
            acc[cb] = __builtin_amdgcn_mfma_f32_16x16x32_bf16(afr, bfr, acc[cb], 0, 0, 0);
        }
    }

    #pragma unroll
    for (int cb = 0; cb < NCB; ++cb) {
        int col = cb * 16 + col0;
        if (col < COUT) {
            #pragma unroll
            for (int i = 0; i < 4; ++i) {
                int row = rowbase + kh * 4 + i;
                float v = acc[cb][i];
                if (ACT) v = v > 0.f ? v : expm1f(v);
                TOUT* dst = &y[(size_t)row * COUT + col];
                if constexpr (__is_same(TOUT, float)) *dst = v;
                else *dst = __float2bfloat16(v);
            }
        }
    }
}

// ---------------- Pool: structured K=4 segment sum, bf16 --------------------
__global__ void __launch_bounds__(256)
pool_kernel(const bf16* __restrict__ x, const int* __restrict__ cols,
            const float* __restrict__ vals, bf16* __restrict__ y,
            int M, int Nin, int C8)
{
    int tid = blockIdx.x * 256 + threadIdx.x;
    int total = BATCH * M * C8;
    if (tid >= total) return;
    int c8 = tid % C8;
    int bm = tid / C8;
    int m = bm % M;
    int b = bm / M;
    float acc[8];
    #pragma unroll
    for (int e = 0; e < 8; ++e) acc[e] = 0.f;
    #pragma unroll
    for (int j = 0; j < 4; ++j) {
        int col = cols[m * 4 + j];
        float v = vals[m * 4 + j];
        uint4 u = ((const uint4*)x)[(size_t)(b * Nin + col) * C8 + c8];
        const bf16* h = (const bf16*)&u;
        #pragma unroll
        for (int e = 0; e < 8; ++e)
            acc[e] = fmaf(v, __bfloat162float(h[e]), acc[e]);
    }
    uint4 o;
    bf16* oh = (bf16*)&o;
    #pragma unroll
    for (int e = 0; e < 8; ++e) oh[e] = __float2bfloat16(acc[e]);
    ((uint4*)y)[(size_t)(b * M + m) * C8 + c8] = o;
}

// ---------------- mu split-K ------------------------------------------------
__global__ void __launch_bounds__(256)
mu_partial_kernel(const bf16* __restrict__ h, const float* __restrict__ W,
                  float* __restrict__ partial)
{
    __shared__ float hs[BATCH * 128];
    const int t = threadIdx.x;
    const int k0 = blockIdx.x * 128;
    for (int e = t; e < BATCH * 128; e += 256) {
        int b = e >> 7, k = e & 127;
        hs[e] = __bfloat162float(h[b * 25600 + k0 + k]);
    }
    __syncthreads();
    const int co = t & 127;
    const int bh = t >> 7;
    float acc[16];
    #pragma unroll
    for (int i = 0; i < 16; ++i) acc[i] = 0.f;
    for (int k = 0; k < 128; ++k) {
        float w = W[(size_t)(k0 + k) * 128 + co];
        #pragma unroll
        for (int i = 0; i < 16; ++i)
            acc[i] = fmaf(hs[(bh * 16 + i) * 128 + k], w, acc[i]);
    }
    float* pb = partial + (size_t)blockIdx.x * 4096;
    #pragma unroll
    for (int i = 0; i < 16; ++i)
        pb[(bh * 16 + i) * 128 + co] = acc[i];
}

__global__ void __launch_bounds__(256)
mu_reduce_kernel(const float* __restrict__ partial, const float* __restrict__ bias,
                 float* __restrict__ z, float* __restrict__ out_z,
                 float* __restrict__ out_mu)
{
    const int i = blockIdx.x * 256 + threadIdx.x;
    const int co = i & 127;
    float a0 = 0.f, a1 = 0.f, a2 = 0.f, a3 = 0.f;
    #pragma unroll 4
    for (int c = 0; c < 200; c += 4) {
        a0 += partial[(size_t)c * 4096 + i];
        a1 += partial[(size_t)(c + 1) * 4096 + i];
        a2 += partial[(size_t)(c + 2) * 4096 + i];
        a3 += partial[(size_t)(c + 3) * 4096 + i];
    }
    float acc = (a0 + a1) + (a2 + a3) + bias[co];
    float m = 1.f / (1.f + expf(-acc));
    z[i] = m;
    out_z[i] = m;
    out_mu[i] = m;
}

// ---------------- d0 = z @ deW0 + deb0 --------------------------------------
__global__ void __launch_bounds__(256)
de0_kernel(const float* __restrict__ z, const float* __restrict__ W,
           const float* __restrict__ bias, bf16* __restrict__ d)
{
    __shared__ float zs[BATCH * 128];
    const int t = threadIdx.x;
    for (int e = t; e < BATCH * 128; e += 256) zs[e] = z[e];
    __syncthreads();
    const int j = blockIdx.x * 256 + t;
    float bj = bias[j];
    float acc[BATCH];
    #pragma unroll
    for (int b = 0; b < BATCH; ++b) acc[b] = bj;
    for (int k = 0; k < 128; ++k) {
        float w = W[k * 25600 + j];
        #pragma unroll
        for (int b = 0; b < BATCH; ++b)
            acc[b] = fmaf(zs[b * 128 + k], w, acc[b]);
    }
    #pragma unroll
    for (int b = 0; b < BATCH; ++b)
        d[b * 25600 + j] = __float2bfloat16(acc[b]);
}

extern "C" void kernel_launch(void* const* d_in, const int* in_sizes, int n_in,
                              void* d_out, int out_size, void* d_ws, size_t ws_size,
                              hipStream_t stream)
{
    const float* x = (const float*)d_in[0];
    const int*   sp[4];
    const int*   dn_cols[4];
    const float* dn_vals[4];
    const int*   up_cols[4];
    const float* up_vals[4];
    const float* enW[4];
    const float* enb[4];
    for (int l = 0; l < 4; ++l) {
        int base = 1 + 9 * l;
        sp[l]      = (const int*)d_in[base + 0];
        dn_cols[l] = (const int*)d_in[base + 2];
        dn_vals[l] = (const float*)d_in[base + 3];
        up_cols[l] = (const int*)d_in[base + 5];
        up_vals[l] = (const float*)d_in[base + 6];
        enW[l]     = (const float*)d_in[base + 7];
        enb[l]     = (const float*)d_in[base + 8];
    }
    const float* muW  = (const float*)d_in[37];
    const float* mub  = (const float*)d_in[38];
    const float* deW0 = (const float*)d_in[39];
    const float* deb0 = (const float*)d_in[40];
    const float* dW[4]  = { (const float*)d_in[41], (const float*)d_in[43],
                            (const float*)d_in[45], (const float*)d_in[47] };
    const float* db[4]  = { (const float*)d_in[42], (const float*)d_in[44],
                            (const float*)d_in[46], (const float*)d_in[48] };
    const float* outW = (const float*)d_in[49];
    const float* outb = (const float*)d_in[50];

    char* ws = (char*)d_ws;
    bf16*  A  = (bf16*)ws;
    bf16*  Bb = (bf16*)(ws + 51200000);
    float* Z  = (float*)(ws + 153600000);
    bf16*  wEN0 = (bf16*)(ws + 153600000 + 16384);
    bf16*  wOUT = wEN0 + 512;

    float* outF   = (float*)d_out;
    float* out_z  = outF + 4800000;
    float* out_mu = outF + 4804096;

    bf16*  wsc  = (bf16*)d_out;
    bf16*  wEN1 = wsc;
    bf16*  wEN2 = wsc + 5120;
    bf16*  wEN3 = wsc + 23552;
    bf16*  wDW0 = wsc + 97280;
    bf16*  wDW1 = wsc + 244736;
    bf16*  wDW2 = wsc + 318464;
    bf16*  wDW3 = wsc + 336896;
    float* muPart = outF + 1000000;

    WcvAll wp;
    const float* srcs[9] = {enW[0], enW[1], enW[2], enW[3], dW[0], dW[1], dW[2], dW[3], outW};
    bf16* dsts[9] = {wEN0, wEN1, wEN2, wEN3, wDW0, wDW1, wDW2, wDW3, wOUT};
    int Ks[9]  = {27, 144, 288, 576, 1152, 1152, 576, 288, 144};
    int COs[9] = {16, 32, 64, 128, 128, 64, 32, 16, 3};
    int KPs[9] = {32, 160, 288, 576, 1152, 1152, 576, 288, 160};
    int COPs[9] = {16, 32, 64, 128, 128, 64, 32, 16, 16};
    int off = 0;
    for (int s = 0; s < 9; ++s) {
        wp.W[s] = srcs[s]; wp.dst[s] = dsts[s];
        wp.K[s] = Ks[s]; wp.CO[s] = COs[s]; wp.KP[s] = KPs[s];
        wp.off[s] = off; off += COPs[s] * KPs[s];
    }
    wp.off[9] = off;
    auto cdiv = [](int a, int b) { return (a + b - 1) / b; };
    wconv_all_kernel<<<cdiv(off, 256), 256, 0, stream>>>(wp);

    auto pool = [&](const bf16* in, const int* cols, const float* vals,
                    bf16* out, int M, int Nin, int C) {
        int C8 = C / 8;
        int total = BATCH * M * C8;
        pool_kernel<<<cdiv(total, 256), 256, 0, stream>>>(in, cols, vals, out, M, Nin, C8);
    };

    // -------- encoder --------
    sconv_mfma<3, 16, 16, 4, 64, 1, NS0, float, bf16><<<BATCH * NS0 / 64, 256, 0, stream>>>(x, sp[0], wEN0, enb[0], A);
    pool(A, dn_cols[0], dn_vals[0], Bb, NS1, NS0, 16);
    sconv_direct<16, 32, 32, 4, 1, NS1, bf16><<<BATCH * NS1 / 64, 256, 0, stream>>>(Bb, sp[1], wEN1, enb[1], A);
    pool(A, dn_cols[1], dn_vals[1], Bb, NS2, NS1, 32);
    sconv_mfma<32, 64, 64, 4, 32, 1, NS2, bf16, bf16><<<BATCH * NS2 / 32, 256, 0, stream>>>(Bb, sp[2], wEN2, enb[2], A);
    pool(A, dn_cols[2], dn_vals[2], Bb, NS3, NS2, 64);
    sconv_mfma<64, 128, 128, 8, 32, 1, NS3, bf16, bf16><<<BATCH * NS3 / 32, 512, 0, stream>>>(Bb, sp[3], wEN3, enb[3], A);
    pool(A, dn_cols[3], dn_vals[3], Bb, NS4, NS3, 128);

    // -------- latent --------
    mu_partial_kernel<<<200, 256, 0, stream>>>(Bb, muW, muPart);
    mu_reduce_kernel<<<16, 256, 0, stream>>>(muPart, mub, Z, out_z, out_mu);
    de0_kernel<<<25600 / 256, 256, 0, stream>>>(Z, deW0, deb0, A);

    // -------- decoder --------
    pool(A, up_cols[3], up_vals[3], Bb, NS3, NS4, 128);
    sconv_mfma<128, 128, 128, 8, 16, 1, NS3, bf16, bf16><<<BATCH * NS3 / 16, 512, 0, stream>>>(Bb, sp[3], wDW0, db[0], A);
    pool(A, up_cols[2], up_vals[2], Bb, NS2, NS3, 128);
    sconv_mfma<128, 64, 64, 4, 16, 1, NS2, bf16, bf16><<<BATCH * NS2 / 16, 256, 0, stream>>>(Bb, sp[2], wDW1, db[1], A);
    pool(A, up_cols[1], up_vals[1], Bb, NS1, NS2, 64);
    sconv_direct<64, 32, 32, 4, 1, NS1, bf16><<<BATCH * NS1 / 64, 256, 0, stream>>>(Bb, sp[1], wDW2, db[2], A);
    pool(A, up_cols[0], up_vals[0], Bb, NS0, NS1, 32);
    sconv_direct<32, 16, 16, 4, 1, NS0, bf16><<<BATCH * NS0 / 64, 256, 0, stream>>>(Bb, sp[0], wDW3, db[3], A);

    // -------- output conv (fp32 into d_out; overwrites scratch) -------------
    sconv_direct<16, 3, 16, 4, 0, NS0, float><<<BATCH * NS0 / 64, 256, 0, stream>>>(A, sp[0], wOUT, outb, outF);
}

// Round 6
// 934.821 us; speedup vs baseline: 7.3331x; 1.0664x over previous
//
#include <hip/hip_runtime.h>
#include <hip/hip_bf16.h>
#include <math.h>

#define NS0 50000
#define NS1 12500
#define NS2 3125
#define NS3 800
#define NS4 200
#define BATCH 32
#define SLEN 9

typedef __hip_bfloat16 bf16;
typedef __attribute__((ext_vector_type(8))) short short8_t;
typedef __attribute__((ext_vector_type(4))) float f32x4;

// ---- fused W conversion: fp32 (K,CO) -> bf16 MFMA-fragment-packed ----------
// layout: dst[(((cb*NKK + kk)*64 + lane)*8 + jj], lane=(kh*16+col0),
//         value = W[k*CO+co], k = kk*32+kh*8+jj, co = cb*16+col0 (0-padded)
struct WcvAll {
    const float* W[9];
    bf16* dst[9];
    int K[9], CO[9], KP[9];
    int off[10];
};

__global__ void __launch_bounds__(256)
wconv_all_kernel(WcvAll p)
{
    int gid = blockIdx.x * 256 + threadIdx.x;
    if (gid >= p.off[9]) return;
    int seg = 0;
    #pragma unroll
    for (int s = 1; s < 9; ++s) seg += (gid >= p.off[s]);
    int local = gid - p.off[seg];
    int NKK = p.KP[seg] >> 5;
    int jj   = local & 7;
    int g8   = local >> 3;
    int lane = g8 & 63;
    int blk  = g8 >> 6;
    int kk   = blk % NKK;
    int cb   = blk / NKK;
    int col0 = lane & 15, kh = lane >> 4;
    int co = cb * 16 + col0;
    int k  = kk * 32 + kh * 8 + jj;
    float v = (k < p.K[seg] && co < p.CO[seg]) ? p.W[seg][k * p.CO[seg] + co] : 0.f;
    p.dst[seg][local] = __float2bfloat16(v);
}

// ---- enc0: CIN=3 LDS-staged MFMA, vertex-major rows (g = n*32 + b) ---------
__global__ void __launch_bounds__(256)
sconv_enc0(const float* __restrict__ x, const int* __restrict__ idx,
           const bf16* __restrict__ Wfrag, const float* __restrict__ bias,
           bf16* __restrict__ y)
{
    __shared__ short lds[64 * 40];           // 64 rows, KP=32 (+8 pad)
    const int t = threadIdx.x;
    const int row0 = blockIdx.x * 64;
    for (int e = t; e < 64 * 5; e += 256) {  // zero k=27..31
        int r = e / 5, k = 27 + (e - r * 5);
        lds[r * 40 + k] = 0;
    }
    for (int e = t; e < 64 * 9; e += 256) {
        int r = e / 9, s = e - r * 9;
        int g = row0 + r;
        int n = g >> 5, b = g & 31;
        int j = idx[n * 9 + s];
        const float* xb = x + ((size_t)b * NS0 + j) * 3;
        short* dst = &lds[r * 40 + s * 3];
        dst[0] = __bfloat16_as_short(__float2bfloat16(xb[0]));
        dst[1] = __bfloat16_as_short(__float2bfloat16(xb[1]));
        dst[2] = __bfloat16_as_short(__float2bfloat16(xb[2]));
    }
    __syncthreads();
    const int w = t >> 6, lane = t & 63;
    const int col0 = lane & 15, kh = lane >> 4;
    const int rbase = w * 16;
    float bv = bias[col0];
    f32x4 acc = (f32x4){bv, bv, bv, bv};
    short8_t bfr = *(const short8_t*)(Wfrag + (size_t)lane * 8);
    short8_t afr = *(const short8_t*)&lds[(rbase + col0) * 40 + kh * 8];
    acc = __builtin_amdgcn_mfma_f32_16x16x32_bf16(afr, bfr, acc, 0, 0, 0);
    #pragma unroll
    for (int i = 0; i < 4; ++i) {
        int g = row0 + rbase + kh * 4 + i;
        float v = acc[i];
        v = v > 0.f ? v : expm1f(v);
        y[(size_t)g * 16 + col0] = __float2bfloat16(v);
    }
}

// ---- vertex-major direct MFMA SpiralConv -----------------------------------
// x: (N, B=32, CIN) bf16 ; wave = 1 vertex, 32 batches (2 row-frags), NCB cols
template<int CIN, int COUT, int COP, int ACT, int NN, int SCATTER, typename TOUT>
__global__ void __launch_bounds__(256)
sconv_vm(const bf16* __restrict__ x, const int* __restrict__ idx,
         const bf16* __restrict__ Wfrag, const float* __restrict__ bias,
         TOUT* __restrict__ y)
{
    constexpr int KP  = (9 * CIN + 31) / 32 * 32;
    constexpr int NKK = KP / 32;
    constexpr int NCB = COP / 16;

    const int t = threadIdx.x, w = t >> 6, lane = t & 63;
    const int n = blockIdx.x * 4 + w;
    if (n >= NN) return;
    const int col0 = lane & 15, kh = lane >> 4;

    int jn[9];
    #pragma unroll
    for (int s = 0; s < 9; ++s) jn[s] = idx[n * 9 + s];

    f32x4 acc[2][NCB];
    #pragma unroll
    for (int cb = 0; cb < NCB; ++cb) {
        int col = cb * 16 + col0;
        float bv = (col < COUT) ? bias[col] : 0.f;
        acc[0][cb] = (f32x4){bv, bv, bv, bv};
        acc[1][cb] = (f32x4){bv, bv, bv, bv};
    }

    const short8_t z8 = {0, 0, 0, 0, 0, 0, 0, 0};
    #pragma unroll
    for (int kk = 0; kk < NKK; ++kk) {
        short8_t a0 = z8, a1 = z8;
        if constexpr (CIN == 16) {
            const int hi = kh >> 1;
            const int ch = (kh & 1) * 8;
            if (kk < 4) {
                int j = hi ? jn[2 * kk + 1] : jn[2 * kk];
                const bf16* base = x + (size_t)j * 512 + ch;
                a0 = *(const short8_t*)(base + col0 * 16);
                a1 = *(const short8_t*)(base + 256 + col0 * 16);
            } else {
                if (!hi) {
                    int j = jn[8];
                    const bf16* base = x + (size_t)j * 512 + ch;
                    a0 = *(const short8_t*)(base + col0 * 16);
                    a1 = *(const short8_t*)(base + 256 + col0 * 16);
                }
            }
        } else {
            constexpr int SPK = CIN / 32;
            const int j = jn[kk / SPK];
            const int ch = (kk % SPK) * 32 + kh * 8;
            const bf16* base = x + (size_t)j * (32 * CIN) + ch;
            a0 = *(const short8_t*)(base + col0 * CIN);
            a1 = *(const short8_t*)(base + (16 + col0) * CIN);
        }
        #pragma unroll
        for (int cb = 0; cb < NCB; ++cb) {
            short8_t bfr = *(const short8_t*)(Wfrag + ((size_t)(cb * NKK + kk) * 64 + lane) * 8);
            acc[0][cb] = __builtin_amdgcn_mfma_f32_16x16x32_bf16(a0, bfr, acc[0][cb], 0, 0, 0);
            acc[1][cb] = __builtin_amdgcn_mfma_f32_16x16x32_bf16(a1, bfr, acc[1][cb], 0, 0, 0);
        }
    }

    #pragma unroll
    for (int f = 0; f < 2; ++f) {
        #pragma unroll
        for (int cb = 0; cb < NCB; ++cb) {
            int col = cb * 16 + col0;
            #pragma unroll
            for (int i = 0; i < 4; ++i) {
                int b = f * 16 + kh * 4 + i;
                float v = acc[f][cb][i];
                if (ACT) v = v > 0.f ? v : expm1f(v);
                if constexpr (SCATTER) {
                    if (col < COUT)
                        y[((size_t)b * NN + n) * COUT + col] = v;   // fp32 (B,N,3)
                } else {
                    y[((size_t)n * 32 + b) * COUT + col] = __float2bfloat16(v);
                }
            }
        }
    }
}

// ---- Pool (vertex-major): y[(m*32+b)*C+c] = sum_j v*x[(col*32+b)*C+c] ------
template<int C8>
__global__ void __launch_bounds__(256)
pool_vm(const bf16* __restrict__ x, const int* __restrict__ cols,
        const float* __restrict__ vals, bf16* __restrict__ y, int M)
{
    constexpr int BC8 = 32 * C8;
    int tid = blockIdx.x * 256 + threadIdx.x;
    if (tid >= M * BC8) return;
    int m = tid / BC8;
    int e = tid - m * BC8;
    const uint4* xv = (const uint4*)x;
    float acc[8];
    #pragma unroll
    for (int q = 0; q < 8; ++q) acc[q] = 0.f;
    #pragma unroll
    for (int j = 0; j < 4; ++j) {
        int col = cols[m * 4 + j];
        float v = vals[m * 4 + j];
        uint4 u = xv[(size_t)col * BC8 + e];
        const bf16* hh = (const bf16*)&u;
        #pragma unroll
        for (int q = 0; q < 8; ++q)
            acc[q] = fmaf(v, __bfloat162float(hh[q]), acc[q]);
    }
    uint4 o;
    bf16* oh = (bf16*)&o;
    #pragma unroll
    for (int q = 0; q < 8; ++q) oh[q] = __float2bfloat16(acc[q]);
    ((uint4*)y)[(size_t)m * BC8 + e] = o;
}

// ---- mu split-K: block = vertex n ; h is (200, 32, 128) vertex-major -------
__global__ void __launch_bounds__(256)
mu_partial_kernel(const bf16* __restrict__ h, const float* __restrict__ W,
                  float* __restrict__ partial)
{
    __shared__ float hs[4096];
    const int t = threadIdx.x;
    const int nb = blockIdx.x;             // 0..199
    const bf16* hb = h + (size_t)nb * 4096;
    for (int e = t; e < 512; e += 256) {
        short8_t v = *(const short8_t*)(hb + e * 8);
        #pragma unroll
        for (int q = 0; q < 8; ++q)
            hs[e * 8 + q] = __bfloat162float(((const bf16*)&v)[q]);
    }
    __syncthreads();
    const int co = t & 127;
    const int bh = t >> 7;
    float acc[16];
    #pragma unroll
    for (int i = 0; i < 16; ++i) acc[i] = 0.f;
    const int k0 = nb * 128;
    for (int k = 0; k < 128; ++k) {
        float wv = W[(size_t)(k0 + k) * 128 + co];
        #pragma unroll
        for (int i = 0; i < 16; ++i)
            acc[i] = fmaf(hs[(bh * 16 + i) * 128 + k], wv, acc[i]);
    }
    float* pb = partial + (size_t)nb * 4096;
    #pragma unroll
    for (int i = 0; i < 16; ++i)
        pb[(bh * 16 + i) * 128 + co] = acc[i];
}

__global__ void __launch_bounds__(256)
mu_reduce_kernel(const float* __restrict__ partial, const float* __restrict__ bias,
                 float* __restrict__ z, float* __restrict__ out_z,
                 float* __restrict__ out_mu)
{
    const int i = blockIdx.x * 256 + threadIdx.x;   // i = b*128 + co
    const int co = i & 127;
    float a0 = 0.f, a1 = 0.f, a2 = 0.f, a3 = 0.f;
    #pragma unroll 4
    for (int c = 0; c < 200; c += 4) {
        a0 += partial[(size_t)c * 4096 + i];
        a1 += partial[(size_t)(c + 1) * 4096 + i];
        a2 += partial[(size_t)(c + 2) * 4096 + i];
        a3 += partial[(size_t)(c + 3) * 4096 + i];
    }
    float acc = (a0 + a1) + (a2 + a3) + bias[co];
    float m = 1.f / (1.f + expf(-acc));
    z[i] = m;
    out_z[i] = m;
    out_mu[i] = m;
}

// ---- d0 = z @ deW0 + deb0, output vertex-major (200, 32, 128) --------------
__global__ void __launch_bounds__(256)
de0_kernel(const float* __restrict__ z, const float* __restrict__ W,
           const float* __restrict__ bias, bf16* __restrict__ d)
{
    __shared__ float zs[BATCH * 128];
    const int t = threadIdx.x;
    for (int e = t; e < BATCH * 128; e += 256) zs[e] = z[e];
    __syncthreads();
    const int j = blockIdx.x * 256 + t;             // j = n*128 + c
    float bj = bias[j];
    float acc[BATCH];
    #pragma unroll
    for (int b = 0; b < BATCH; ++b) acc[b] = bj;
    for (int k = 0; k < 128; ++k) {
        float w = W[k * 25600 + j];
        #pragma unroll
        for (int b = 0; b < BATCH; ++b)
            acc[b] = fmaf(zs[b * 128 + k], w, acc[b]);
    }
    const int nn = j >> 7, c = j & 127;
    #pragma unroll
    for (int b = 0; b < BATCH; ++b)
        d[(size_t)nn * 4096 + b * 128 + c] = __float2bfloat16(acc[b]);
}

extern "C" void kernel_launch(void* const* d_in, const int* in_sizes, int n_in,
                              void* d_out, int out_size, void* d_ws, size_t ws_size,
                              hipStream_t stream)
{
    const float* x = (const float*)d_in[0];
    const int*   sp[4];
    const int*   dn_cols[4];
    const float* dn_vals[4];
    const int*   up_cols[4];
    const float* up_vals[4];
    const float* enW[4];
    const float* enb[4];
    for (int l = 0; l < 4; ++l) {
        int base = 1 + 9 * l;
        sp[l]      = (const int*)d_in[base + 0];
        dn_cols[l] = (const int*)d_in[base + 2];
        dn_vals[l] = (const float*)d_in[base + 3];
        up_cols[l] = (const int*)d_in[base + 5];
        up_vals[l] = (const float*)d_in[base + 6];
        enW[l]     = (const float*)d_in[base + 7];
        enb[l]     = (const float*)d_in[base + 8];
    }
    const float* muW  = (const float*)d_in[37];
    const float* mub  = (const float*)d_in[38];
    const float* deW0 = (const float*)d_in[39];
    const float* deb0 = (const float*)d_in[40];
    const float* dW[4]  = { (const float*)d_in[41], (const float*)d_in[43],
                            (const float*)d_in[45], (const float*)d_in[47] };
    const float* db[4]  = { (const float*)d_in[42], (const float*)d_in[44],
                            (const float*)d_in[46], (const float*)d_in[48] };
    const float* outW = (const float*)d_in[49];
    const float* outb = (const float*)d_in[50];

    char* ws = (char*)d_ws;
    bf16*  A  = (bf16*)ws;                        // 25.6M bf16 cap
    bf16*  Bb = (bf16*)(ws + 51200000);           // 51.2M bf16 cap
    float* Z  = (float*)(ws + 153600000);
    bf16*  wEN0 = (bf16*)(ws + 153600000 + 16384);
    bf16*  wOUT = wEN0 + 512;

    float* outF   = (float*)d_out;
    float* out_z  = outF + 4800000;
    float* out_mu = outF + 4804096;

    // scratch inside d_out conv region (overwritten by the final conv):
    bf16*  wsc  = (bf16*)d_out;
    bf16*  wEN1 = wsc;            // 5120
    bf16*  wEN2 = wsc + 5120;     // 18432
    bf16*  wEN3 = wsc + 23552;    // 73728
    bf16*  wDW0 = wsc + 97280;    // 147456
    bf16*  wDW1 = wsc + 244736;   // 73728
    bf16*  wDW2 = wsc + 318464;   // 18432
    bf16*  wDW3 = wsc + 336896;   // 4608
    float* muPart = outF + 1000000;   // 200*4096 f32

    WcvAll wp;
    const float* srcs[9] = {enW[0], enW[1], enW[2], enW[3], dW[0], dW[1], dW[2], dW[3], outW};
    bf16* dsts[9] = {wEN0, wEN1, wEN2, wEN3, wDW0, wDW1, wDW2, wDW3, wOUT};
    int Ks[9]   = {27, 144, 288, 576, 1152, 1152, 576, 288, 144};
    int COs[9]  = {16, 32, 64, 128, 128, 64, 32, 16, 3};
    int KPs[9]  = {32, 160, 288, 576, 1152, 1152, 576, 288, 160};
    int COPs[9] = {16, 32, 64, 128, 128, 64, 32, 16, 16};
    int off = 0;
    for (int s = 0; s < 9; ++s) {
        wp.W[s] = srcs[s]; wp.dst[s] = dsts[s];
        wp.K[s] = Ks[s]; wp.CO[s] = COs[s]; wp.KP[s] = KPs[s];
        wp.off[s] = off; off += COPs[s] * KPs[s];
    }
    wp.off[9] = off;
    auto cdiv = [](int a, int b) { return (a + b - 1) / b; };
    wconv_all_kernel<<<cdiv(off, 256), 256, 0, stream>>>(wp);

    // -------- encoder (activations vertex-major (N, 32, C)) --------
    sconv_enc0<<<BATCH * NS0 / 64, 256, 0, stream>>>(x, sp[0], wEN0, enb[0], A);
    pool_vm<2><<<cdiv(NS1 * 64, 256), 256, 0, stream>>>(A, dn_cols[0], dn_vals[0], Bb, NS1);
    sconv_vm<16, 32, 32, 1, NS1, 0, bf16><<<cdiv(NS1, 4), 256, 0, stream>>>(Bb, sp[1], wEN1, enb[1], A);
    pool_vm<4><<<cdiv(NS2 * 128, 256), 256, 0, stream>>>(A, dn_cols[1], dn_vals[1], Bb, NS2);
    sconv_vm<32, 64, 64, 1, NS2, 0, bf16><<<cdiv(NS2, 4), 256, 0, stream>>>(Bb, sp[2], wEN2, enb[2], A);
    pool_vm<8><<<cdiv(NS3 * 256, 256), 256, 0, stream>>>(A, dn_cols[2], dn_vals[2], Bb, NS3);
    sconv_vm<64, 128, 128, 1, NS3, 0, bf16><<<cdiv(NS3, 4), 256, 0, stream>>>(Bb, sp[3], wEN3, enb[3], A);
    pool_vm<16><<<cdiv(NS4 * 512, 256), 256, 0, stream>>>(A, dn_cols[3], dn_vals[3], Bb, NS4);

    // -------- latent --------
    mu_partial_kernel<<<200, 256, 0, stream>>>(Bb, muW, muPart);
    mu_reduce_kernel<<<16, 256, 0, stream>>>(muPart, mub, Z, out_z, out_mu);
    de0_kernel<<<25600 / 256, 256, 0, stream>>>(Z, deW0, deb0, A);

    // -------- decoder --------
    pool_vm<16><<<cdiv(NS3 * 512, 256), 256, 0, stream>>>(A, up_cols[3], up_vals[3], Bb, NS3);
    sconv_vm<128, 128, 128, 1, NS3, 0, bf16><<<cdiv(NS3, 4), 256, 0, stream>>>(Bb, sp[3], wDW0, db[0], A);
    pool_vm<16><<<cdiv(NS2 * 512, 256), 256, 0, stream>>>(A, up_cols[2], up_vals[2], Bb, NS2);
    sconv_vm<128, 64, 64, 1, NS2, 0, bf16><<<cdiv(NS2, 4), 256, 0, stream>>>(Bb, sp[2], wDW1, db[1], A);
    pool_vm<8><<<cdiv(NS1 * 256, 256), 256, 0, stream>>>(A, up_cols[1], up_vals[1], Bb, NS1);
    sconv_vm<64, 32, 32, 1, NS1, 0, bf16><<<cdiv(NS1, 4), 256, 0, stream>>>(Bb, sp[1], wDW2, db[2], A);
    pool_vm<4><<<cdiv(NS0 * 128, 256), 256, 0, stream>>>(A, up_cols[0], up_vals[0], Bb, NS0);
    sconv_vm<32, 16, 16, 1, NS0, 0, bf16><<<cdiv(NS0, 4), 256, 0, stream>>>(Bb, sp[0], wDW3, db[3], A);

    // -------- output conv: scatter-store fp32 (B, N0, 3) into d_out ---------
    sconv_vm<16, 3, 16, 0, NS0, 1, float><<<cdiv(NS0, 4), 256, 0, stream>>>(A, sp[0], wOUT, outb, outF);
}

// Round 7
// 821.327 us; speedup vs baseline: 8.3464x; 1.1382x over previous
//
#include <hip/hip_runtime.h>
#include <hip/hip_bf16.h>
#include <math.h>

#define NS0 50000
#define NS1 12500
#define NS2 3125
#define NS3 800
#define NS4 200
#define BATCH 32
#define SLEN 9

typedef __hip_bfloat16 bf16;
typedef __attribute__((ext_vector_type(8))) short short8_t;
typedef __attribute__((ext_vector_type(4))) float f32x4;

// ---- fused W conversion: fp32 (K,CO) -> bf16 MFMA-fragment-packed ----------
struct WcvAll {
    const float* W[9];
    bf16* dst[9];
    int K[9], CO[9], KP[9];
    int off[10];
};

__global__ void __launch_bounds__(256)
wconv_all_kernel(WcvAll p)
{
    int gid = blockIdx.x * 256 + threadIdx.x;
    if (gid >= p.off[9]) return;
    int seg = 0;
    #pragma unroll
    for (int s = 1; s < 9; ++s) seg += (gid >= p.off[s]);
    int local = gid - p.off[seg];
    int NKK = p.KP[seg] >> 5;
    int jj   = local & 7;
    int g8   = local >> 3;
    int lane = g8 & 63;
    int blk  = g8 >> 6;
    int kk   = blk % NKK;
    int cb   = blk / NKK;
    int col0 = lane & 15, kh = lane >> 4;
    int co = cb * 16 + col0;
    int k  = kk * 32 + kh * 8 + jj;
    float v = (k < p.K[seg] && co < p.CO[seg]) ? p.W[seg][k * p.CO[seg] + co] : 0.f;
    p.dst[seg][local] = __float2bfloat16(v);
}

// ---- transpose x: fp32 (B, N0, 3) -> bf16 (N0, 32, 3) ----------------------
__global__ void __launch_bounds__(256)
xpose_in_kernel(const float* __restrict__ x, bf16* __restrict__ xT)
{
    int tid = blockIdx.x * 256 + threadIdx.x;      // tid = b*NS0 + n
    if (tid >= BATCH * NS0) return;
    int b = tid / NS0, n = tid - b * NS0;
    const float* src = x + (size_t)tid * 3;        // coalesced 12B reads
    bf16* dst = xT + ((size_t)n * 32 + b) * 3;
    dst[0] = __float2bfloat16(src[0]);
    dst[1] = __float2bfloat16(src[1]);
    dst[2] = __float2bfloat16(src[2]);
}

// ---- transpose out: fp32 (N0, 32, 3) -> fp32 (B, N0, 3) --------------------
__global__ void __launch_bounds__(256)
xpose_out_kernel(const float* __restrict__ vm, float* __restrict__ out)
{
    int tid = blockIdx.x * 256 + threadIdx.x;      // tid = b*NS0 + n
    if (tid >= BATCH * NS0) return;
    int b = tid / NS0, n = tid - b * NS0;
    const float* src = vm + ((size_t)n * 32 + b) * 3;
    float* dst = out + (size_t)tid * 3;            // coalesced 12B writes
    dst[0] = src[0];
    dst[1] = src[1];
    dst[2] = src[2];
}

// ---- enc0: CIN=3 LDS-staged MFMA from vertex-major xT (N0, 32, 3) ----------
__global__ void __launch_bounds__(256)
sconv_enc0(const bf16* __restrict__ xT, const int* __restrict__ idx,
           const bf16* __restrict__ Wfrag, const float* __restrict__ bias,
           bf16* __restrict__ y)
{
    __shared__ short lds[64 * 40];                 // 64 rows (2 vertices x 32 b), KP=32 (+8 pad)
    const int t = threadIdx.x;
    const int n0 = blockIdx.x * 2;

    for (int e = t; e < 64 * 5; e += 256) {        // zero k=27..31
        int r = e / 5, k = 27 + (e - r * 5);
        lds[r * 40 + k] = 0;
    }
    for (int e = t; e < 2 * 9 * 32; e += 256) {    // 576: (v, s, b)
        int v = e / 288;
        int rem = e - v * 288;
        int s = rem >> 5, b = rem & 31;
        int j = idx[(n0 + v) * 9 + s];
        const short* src = (const short*)(xT + (size_t)j * 96 + b * 3);
        short* dst = &lds[(v * 32 + b) * 40 + s * 3];
        dst[0] = src[0];
        dst[1] = src[1];
        dst[2] = src[2];
    }
    __syncthreads();

    const int w = t >> 6, lane = t & 63;
    const int col0 = lane & 15, kh = lane >> 4;
    const int rbase = w * 16;
    float bv = bias[col0];
    f32x4 acc = (f32x4){bv, bv, bv, bv};
    short8_t bfr = *(const short8_t*)(Wfrag + (size_t)lane * 8);
    short8_t afr = *(const short8_t*)&lds[(rbase + col0) * 40 + kh * 8];
    acc = __builtin_amdgcn_mfma_f32_16x16x32_bf16(afr, bfr, acc, 0, 0, 0);
    #pragma unroll
    for (int i = 0; i < 4; ++i) {
        int rl = rbase + kh * 4 + i;               // local row = v*32 + b
        float v = acc[i];
        v = v > 0.f ? v : expm1f(v);
        y[((size_t)n0 * 32 + rl) * 16 + col0] = __float2bfloat16(v);
    }
}

// ---- vertex-major direct MFMA SpiralConv -----------------------------------
// x: (N, 32, CIN) bf16 ; wave = 1 vertex, 32 batches (2 row-frags), NCB cols
template<int CIN, int COUT, int COP, int ACT, int NN, typename TOUT>
__global__ void __launch_bounds__(256)
sconv_vm(const bf16* __restrict__ x, const int* __restrict__ idx,
         const bf16* __restrict__ Wfrag, const float* __restrict__ bias,
         TOUT* __restrict__ y)
{
    constexpr int KP  = (9 * CIN + 31) / 32 * 32;
    constexpr int NKK = KP / 32;
    constexpr int NCB = COP / 16;

    const int t = threadIdx.x, w = t >> 6, lane = t & 63;
    const int n = blockIdx.x * 4 + w;
    if (n >= NN) return;
    const int col0 = lane & 15, kh = lane >> 4;

    int jn[9];
    #pragma unroll
    for (int s = 0; s < 9; ++s) jn[s] = idx[n * 9 + s];

    f32x4 acc[2][NCB];
    #pragma unroll
    for (int cb = 0; cb < NCB; ++cb) {
        int col = cb * 16 + col0;
        float bv = (col < COUT) ? bias[col] : 0.f;
        acc[0][cb] = (f32x4){bv, bv, bv, bv};
        acc[1][cb] = (f32x4){bv, bv, bv, bv};
    }

    const short8_t z8 = {0, 0, 0, 0, 0, 0, 0, 0};
    #pragma unroll
    for (int kk = 0; kk < NKK; ++kk) {
        short8_t a0 = z8, a1 = z8;
        if constexpr (CIN == 16) {
            const int hi = kh >> 1;
            const int ch = (kh & 1) * 8;
            if (kk < 4) {
                int j = hi ? jn[2 * kk + 1] : jn[2 * kk];
                const bf16* base = x + (size_t)j * 512 + ch;
                a0 = *(const short8_t*)(base + col0 * 16);
                a1 = *(const short8_t*)(base + 256 + col0 * 16);
            } else {
                if (!hi) {
                    int j = jn[8];
                    const bf16* base = x + (size_t)j * 512 + ch;
                    a0 = *(const short8_t*)(base + col0 * 16);
                    a1 = *(const short8_t*)(base + 256 + col0 * 16);
                }
            }
        } else {
            constexpr int SPK = CIN / 32;
            const int j = jn[kk / SPK];
            const int ch = (kk % SPK) * 32 + kh * 8;
            const bf16* base = x + (size_t)j * (32 * CIN) + ch;
            a0 = *(const short8_t*)(base + col0 * CIN);
            a1 = *(const short8_t*)(base + (16 + col0) * CIN);
        }
        #pragma unroll
        for (int cb = 0; cb < NCB; ++cb) {
            short8_t bfr = *(const short8_t*)(Wfrag + ((size_t)(cb * NKK + kk) * 64 + lane) * 8);
            acc[0][cb] = __builtin_amdgcn_mfma_f32_16x16x32_bf16(a0, bfr, acc[0][cb], 0, 0, 0);
            acc[1][cb] = __builtin_amdgcn_mfma_f32_16x16x32_bf16(a1, bfr, acc[1][cb], 0, 0, 0);
        }
    }

    #pragma unroll
    for (int f = 0; f < 2; ++f) {
        #pragma unroll
        for (int cb = 0; cb < NCB; ++cb) {
            int col = cb * 16 + col0;
            if (col < COUT) {
                #pragma unroll
                for (int i = 0; i < 4; ++i) {
                    int b = f * 16 + kh * 4 + i;
                    float v = acc[f][cb][i];
                    if (ACT) v = v > 0.f ? v : expm1f(v);
                    TOUT* dst = &y[((size_t)n * 32 + b) * COUT + col];
                    if constexpr (__is_same(TOUT, float)) *dst = v;
                    else *dst = __float2bfloat16(v);
                }
            }
        }
    }
}

// ---- Pool (vertex-major): y[(m*32+b)*C+c] = sum_j v*x[(col*32+b)*C+c] ------
template<int C8>
__global__ void __launch_bounds__(256)
pool_vm(const bf16* __restrict__ x, const int* __restrict__ cols,
        const float* __restrict__ vals, bf16* __restrict__ y, int M)
{
    constexpr int BC8 = 32 * C8;
    int tid = blockIdx.x * 256 + threadIdx.x;
    if (tid >= M * BC8) return;
    int m = tid / BC8;
    int e = tid - m * BC8;
    const uint4* xv = (const uint4*)x;
    float acc[8];
    #pragma unroll
    for (int q = 0; q < 8; ++q) acc[q] = 0.f;
    #pragma unroll
    for (int j = 0; j < 4; ++j) {
        int col = cols[m * 4 + j];
        float v = vals[m * 4 + j];
        uint4 u = xv[(size_t)col * BC8 + e];
        const bf16* hh = (const bf16*)&u;
        #pragma unroll
        for (int q = 0; q < 8; ++q)
            acc[q] = fmaf(v, __bfloat162float(hh[q]), acc[q]);
    }
    uint4 o;
    bf16* oh = (bf16*)&o;
    #pragma unroll
    for (int q = 0; q < 8; ++q) oh[q] = __float2bfloat16(acc[q]);
    ((uint4*)y)[(size_t)m * BC8 + e] = o;
}

// ---- mu split-K: block = vertex n ; h is (200, 32, 128) vertex-major -------
__global__ void __launch_bounds__(256)
mu_partial_kernel(const bf16* __restrict__ h, const float* __restrict__ W,
                  float* __restrict__ partial)
{
    __shared__ float hs[4096];
    const int t = threadIdx.x;
    const int nb = blockIdx.x;             // 0..199
    const bf16* hb = h + (size_t)nb * 4096;
    for (int e = t; e < 512; e += 256) {
        short8_t v = *(const short8_t*)(hb + e * 8);
        #pragma unroll
        for (int q = 0; q < 8; ++q)
            hs[e * 8 + q] = __bfloat162float(((const bf16*)&v)[q]);
    }
    __syncthreads();
    const int co = t & 127;
    const int bh = t >> 7;
    float acc[16];
    #pragma unroll
    for (int i = 0; i < 16; ++i) acc[i] = 0.f;
    const int k0 = nb * 128;
    for (int k = 0; k < 128; ++k) {
        float wv = W[(size_t)(k0 + k) * 128 + co];
        #pragma unroll
        for (int i = 0; i < 16; ++i)
            acc[i] = fmaf(hs[(bh * 16 + i) * 128 + k], wv, acc[i]);
    }
    float* pb = partial + (size_t)nb * 4096;
    #pragma unroll
    for (int i = 0; i < 16; ++i)
        pb[(bh * 16 + i) * 128 + co] = acc[i];
}

__global__ void __launch_bounds__(256)
mu_reduce_kernel(const float* __restrict__ partial, const float* __restrict__ bias,
                 float* __restrict__ z, float* __restrict__ out_z,
                 float* __restrict__ out_mu)
{
    const int i = blockIdx.x * 256 + threadIdx.x;   // i = b*128 + co
    const int co = i & 127;
    float a0 = 0.f, a1 = 0.f, a2 = 0.f, a3 = 0.f;
    #pragma unroll 4
    for (int c = 0; c < 200; c += 4) {
        a0 += partial[(size_t)c * 4096 + i];
        a1 += partial[(size_t)(c + 1) * 4096 + i];
        a2 += partial[(size_t)(c + 2) * 4096 + i];
        a3 += partial[(size_t)(c + 3) * 4096 + i];
    }
    float acc = (a0 + a1) + (a2 + a3) + bias[co];
    float m = 1.f / (1.f + expf(-acc));
    z[i] = m;
    out_z[i] = m;
    out_mu[i] = m;
}

// ---- d0 = z @ deW0 + deb0, output vertex-major (200, 32, 128) --------------
__global__ void __launch_bounds__(256)
de0_kernel(const float* __restrict__ z, const float* __restrict__ W,
           const float* __restrict__ bias, bf16* __restrict__ d)
{
    __shared__ float zs[BATCH * 128];
    const int t = threadIdx.x;
    for (int e = t; e < BATCH * 128; e += 256) zs[e] = z[e];
    __syncthreads();
    const int j = blockIdx.x * 256 + t;             // j = n*128 + c
    float bj = bias[j];
    float acc[BATCH];
    #pragma unroll
    for (int b = 0; b < BATCH; ++b) acc[b] = bj;
    for (int k = 0; k < 128; ++k) {
        float w = W[k * 25600 + j];
        #pragma unroll
        for (int b = 0; b < BATCH; ++b)
            acc[b] = fmaf(zs[b * 128 + k], w, acc[b]);
    }
    const int nn = j >> 7, c = j & 127;
    #pragma unroll
    for (int b = 0; b < BATCH; ++b)
        d[(size_t)nn * 4096 + b * 128 + c] = __float2bfloat16(acc[b]);
}

extern "C" void kernel_launch(void* const* d_in, const int* in_sizes, int n_in,
                              void* d_out, int out_size, void* d_ws, size_t ws_size,
                              hipStream_t stream)
{
    const float* x = (const float*)d_in[0];
    const int*   sp[4];
    const int*   dn_cols[4];
    const float* dn_vals[4];
    const int*   up_cols[4];
    const float* up_vals[4];
    const float* enW[4];
    const float* enb[4];
    for (int l = 0; l < 4; ++l) {
        int base = 1 + 9 * l;
        sp[l]      = (const int*)d_in[base + 0];
        dn_cols[l] = (const int*)d_in[base + 2];
        dn_vals[l] = (const float*)d_in[base + 3];
        up_cols[l] = (const int*)d_in[base + 5];
        up_vals[l] = (const float*)d_in[base + 6];
        enW[l]     = (const float*)d_in[base + 7];
        enb[l]     = (const float*)d_in[base + 8];
    }
    const float* muW  = (const float*)d_in[37];
    const float* mub  = (const float*)d_in[38];
    const float* deW0 = (const float*)d_in[39];
    const float* deb0 = (const float*)d_in[40];
    const float* dW[4]  = { (const float*)d_in[41], (const float*)d_in[43],
                            (const float*)d_in[45], (const float*)d_in[47] };
    const float* db[4]  = { (const float*)d_in[42], (const float*)d_in[44],
                            (const float*)d_in[46], (const float*)d_in[48] };
    const float* outW = (const float*)d_in[49];
    const float* outb = (const float*)d_in[50];

    char* ws = (char*)d_ws;
    bf16*  A  = (bf16*)ws;                        // [0, 51.2MB)
    bf16*  Bb = (bf16*)(ws + 51200000);           // [51.2MB, 153.6MB)
    bf16*  xT = (bf16*)(ws + 51200000);           // overlaps Bb: dead before pool dn0
    float* outVM = (float*)(ws + 51200000);       // overlaps Bb: dead after dW3 conv
    float* Z  = (float*)(ws + 153600000);
    bf16*  wEN0 = (bf16*)(ws + 153600000 + 16384);
    bf16*  wOUT = wEN0 + 512;

    float* outF   = (float*)d_out;
    float* out_z  = outF + 4800000;
    float* out_mu = outF + 4804096;

    // scratch inside d_out conv region (overwritten by the final transpose):
    bf16*  wsc  = (bf16*)d_out;
    bf16*  wEN1 = wsc;            // 5120
    bf16*  wEN2 = wsc + 5120;     // 18432
    bf16*  wEN3 = wsc + 23552;    // 73728
    bf16*  wDW0 = wsc + 97280;    // 147456
    bf16*  wDW1 = wsc + 244736;   // 73728
    bf16*  wDW2 = wsc + 318464;   // 18432
    bf16*  wDW3 = wsc + 336896;   // 4608
    float* muPart = outF + 1000000;   // 200*4096 f32

    WcvAll wp;
    const float* srcs[9] = {enW[0], enW[1], enW[2], enW[3], dW[0], dW[1], dW[2], dW[3], outW};
    bf16* dsts[9] = {wEN0, wEN1, wEN2, wEN3, wDW0, wDW1, wDW2, wDW3, wOUT};
    int Ks[9]   = {27, 144, 288, 576, 1152, 1152, 576, 288, 144};
    int COs[9]  = {16, 32, 64, 128, 128, 64, 32, 16, 3};
    int KPs[9]  = {32, 160, 288, 576, 1152, 1152, 576, 288, 160};
    int COPs[9] = {16, 32, 64, 128, 128, 64, 32, 16, 16};
    int off = 0;
    for (int s = 0; s < 9; ++s) {
        wp.W[s] = srcs[s]; wp.dst[s] = dsts[s];
        wp.K[s] = Ks[s]; wp.CO[s] = COs[s]; wp.KP[s] = KPs[s];
        wp.off[s] = off; off += COPs[s] * KPs[s];
    }
    wp.off[9] = off;
    auto cdiv = [](int a, int b) { return (a + b - 1) / b; };
    wconv_all_kernel<<<cdiv(off, 256), 256, 0, stream>>>(wp);

    // -------- input transpose to vertex-major --------
    xpose_in_kernel<<<cdiv(BATCH * NS0, 256), 256, 0, stream>>>(x, xT);

    // -------- encoder (activations vertex-major (N, 32, C)) --------
    sconv_enc0<<<NS0 / 2, 256, 0, stream>>>(xT, sp[0], wEN0, enb[0], A);
    pool_vm<2><<<cdiv(NS1 * 64, 256), 256, 0, stream>>>(A, dn_cols[0], dn_vals[0], Bb, NS1);
    sconv_vm<16, 32, 32, 1, NS1, bf16><<<cdiv(NS1, 4), 256, 0, stream>>>(Bb, sp[1], wEN1, enb[1], A);
    pool_vm<4><<<cdiv(NS2 * 128, 256), 256, 0, stream>>>(A, dn_cols[1], dn_vals[1], Bb, NS2);
    sconv_vm<32, 64, 64, 1, NS2, bf16><<<cdiv(NS2, 4), 256, 0, stream>>>(Bb, sp[2], wEN2, enb[2], A);
    pool_vm<8><<<cdiv(NS3 * 256, 256), 256, 0, stream>>>(A, dn_cols[2], dn_vals[2], Bb, NS3);
    sconv_vm<64, 128, 128, 1, NS3, bf16><<<cdiv(NS3, 4), 256, 0, stream>>>(Bb, sp[3], wEN3, enb[3], A);
    pool_vm<16><<<cdiv(NS4 * 512, 256), 256, 0, stream>>>(A, dn_cols[3], dn_vals[3], Bb, NS4);

    // -------- latent --------
    mu_partial_kernel<<<200, 256, 0, stream>>>(Bb, muW, muPart);
    mu_reduce_kernel<<<16, 256, 0, stream>>>(muPart, mub, Z, out_z, out_mu);
    de0_kernel<<<25600 / 256, 256, 0, stream>>>(Z, deW0, deb0, A);

    // -------- decoder --------
    pool_vm<16><<<cdiv(NS3 * 512, 256), 256, 0, stream>>>(A, up_cols[3], up_vals[3], Bb, NS3);
    sconv_vm<128, 128, 128, 1, NS3, bf16><<<cdiv(NS3, 4), 256, 0, stream>>>(Bb, sp[3], wDW0, db[0], A);
    pool_vm<16><<<cdiv(NS2 * 512, 256), 256, 0, stream>>>(A, up_cols[2], up_vals[2], Bb, NS2);
    sconv_vm<128, 64, 64, 1, NS2, bf16><<<cdiv(NS2, 4), 256, 0, stream>>>(Bb, sp[2], wDW1, db[1], A);
    pool_vm<8><<<cdiv(NS1 * 256, 256), 256, 0, stream>>>(A, up_cols[1], up_vals[1], Bb, NS1);
    sconv_vm<64, 32, 32, 1, NS1, bf16><<<cdiv(NS1, 4), 256, 0, stream>>>(Bb, sp[1], wDW2, db[2], A);
    pool_vm<4><<<cdiv(NS0 * 128, 256), 256, 0, stream>>>(A, up_cols[0], up_vals[0], Bb, NS0);
    sconv_vm<32, 16, 16, 1, NS0, bf16><<<cdiv(NS0, 4), 256, 0, stream>>>(Bb, sp[0], wDW3, db[3], A);

    // -------- output conv: vertex-major fp32 into ws, then transpose --------
    sconv_vm<16, 3, 16, 0, NS0, float><<<cdiv(NS0, 4), 256, 0, stream>>>(A, sp[0], wOUT, outb, outVM);
    xpose_out_kernel<<<cdiv(BATCH * NS0, 256), 256, 0, stream>>>(outVM, outF);
}

// Round 8
// 756.749 us; speedup vs baseline: 9.0586x; 1.0853x over previous
//
#include <hip/hip_runtime.h>
#include <hip/hip_bf16.h>
#include <math.h>

#define NS0 50000
#define NS1 12500
#define NS2 3125
#define NS3 800
#define NS4 200
#define BATCH 32
#define SLEN 9

typedef __hip_bfloat16 bf16;
typedef __attribute__((ext_vector_type(8))) short short8_t;
typedef __attribute__((ext_vector_type(4))) float f32x4;

// ---- fused W conversion: fp32 (K,CO) -> bf16 MFMA-fragment-packed ----------
struct WcvAll {
    const float* W[9];
    bf16* dst[9];
    int K[9], CO[9], KP[9];
    int off[10];
};

__global__ void __launch_bounds__(256)
wconv_all_kernel(WcvAll p)
{
    int gid = blockIdx.x * 256 + threadIdx.x;
    if (gid >= p.off[9]) return;
    int seg = 0;
    #pragma unroll
    for (int s = 1; s < 9; ++s) seg += (gid >= p.off[s]);
    int local = gid - p.off[seg];
    int NKK = p.KP[seg] >> 5;
    int jj   = local & 7;
    int g8   = local >> 3;
    int lane = g8 & 63;
    int blk  = g8 >> 6;
    int kk   = blk % NKK;
    int cb   = blk / NKK;
    int col0 = lane & 15, kh = lane >> 4;
    int co = cb * 16 + col0;
    int k  = kk * 32 + kh * 8 + jj;
    float v = (k < p.K[seg] && co < p.CO[seg]) ? p.W[seg][k * p.CO[seg] + co] : 0.f;
    p.dst[seg][local] = __float2bfloat16(v);
}

// ---- transpose x: fp32 (B, N0, 3) -> bf16 (N0, 32, 3), LDS-tiled -----------
__global__ void __launch_bounds__(256)
xpose_in_kernel(const float* __restrict__ x, bf16* __restrict__ xT)
{
    __shared__ short ldsb[256 * 3];
    const int t = threadIdx.x;
    const int n0 = blockIdx.x * 8;
    const int b = t >> 3, v = t & 7;
    const float* src = x + ((size_t)b * NS0 + n0 + v) * 3;   // 96B chunks per 8 threads
    short* d = &ldsb[(v * 32 + b) * 3];
    d[0] = __bfloat16_as_short(__float2bfloat16(src[0]));
    d[1] = __bfloat16_as_short(__float2bfloat16(src[1]));
    d[2] = __bfloat16_as_short(__float2bfloat16(src[2]));
    __syncthreads();
    short* dst = (short*)xT + ((size_t)n0 * 32 + t) * 3;     // contiguous 1.5KB/block
    dst[0] = ldsb[t * 3 + 0];
    dst[1] = ldsb[t * 3 + 1];
    dst[2] = ldsb[t * 3 + 2];
}

// ---- transpose out: fp32 (N0, 32, 3) -> fp32 (B, N0, 3), LDS-tiled ---------
__global__ void __launch_bounds__(256)
xpose_out_kernel(const float* __restrict__ vm, float* __restrict__ out)
{
    __shared__ float ldsf[256 * 3];
    const int t = threadIdx.x;
    const int n0 = blockIdx.x * 8;
    const float* src = vm + ((size_t)n0 * 32 + t) * 3;       // contiguous 3KB/block
    ldsf[t * 3 + 0] = src[0];
    ldsf[t * 3 + 1] = src[1];
    ldsf[t * 3 + 2] = src[2];
    __syncthreads();
    const int b = t >> 3, v = t & 7;
    float* dst = out + ((size_t)b * NS0 + n0 + v) * 3;       // 96B chunks per 8 threads
    const float* s = &ldsf[(v * 32 + b) * 3];
    dst[0] = s[0];
    dst[1] = s[1];
    dst[2] = s[2];
}

// ---- enc0: CIN=3 LDS-staged MFMA from vertex-major xT (N0, 32, 3) ----------
__global__ void __launch_bounds__(256)
sconv_enc0(const bf16* __restrict__ xT, const int* __restrict__ idx,
           const bf16* __restrict__ Wfrag, const float* __restrict__ bias,
           bf16* __restrict__ y)
{
    __shared__ short lds[64 * 40];
    const int t = threadIdx.x;
    const int n0 = blockIdx.x * 2;

    for (int e = t; e < 64 * 5; e += 256) {
        int r = e / 5, k = 27 + (e - r * 5);
        lds[r * 40 + k] = 0;
    }
    for (int e = t; e < 2 * 9 * 32; e += 256) {
        int v = e / 288;
        int rem = e - v * 288;
        int s = rem >> 5, b = rem & 31;
        int j = idx[(n0 + v) * 9 + s];
        const short* src = (const short*)(xT + (size_t)j * 96 + b * 3);
        short* dst = &lds[(v * 32 + b) * 40 + s * 3];
        dst[0] = src[0];
        dst[1] = src[1];
        dst[2] = src[2];
    }
    __syncthreads();

    const int w = t >> 6, lane = t & 63;
    const int col0 = lane & 15, kh = lane >> 4;
    const int rbase = w * 16;
    float bv = bias[col0];
    f32x4 acc = (f32x4){bv, bv, bv, bv};
    short8_t bfr = *(const short8_t*)(Wfrag + (size_t)lane * 8);
    short8_t afr = *(const short8_t*)&lds[(rbase + col0) * 40 + kh * 8];
    acc = __builtin_amdgcn_mfma_f32_16x16x32_bf16(afr, bfr, acc, 0, 0, 0);
    #pragma unroll
    for (int i = 0; i < 4; ++i) {
        int rl = rbase + kh * 4 + i;
        float v = acc[i];
        v = v > 0.f ? v : expm1f(v);
        y[((size_t)n0 * 32 + rl) * 16 + col0] = __float2bfloat16(v);
    }
}

// ---- vertex-major direct MFMA SpiralConv, register-prefetched gathers ------
// x: (N, 32, CIN) bf16 ; wave = 1 vertex, 32 batches (2 row-frags), NCB cols
// A-fragment loads for a chunk of CH k-steps are issued before the MFMAs that
// consume them (double-buffered across chunks) to maximize loads in flight.
template<int CIN, int COUT, int COP, int ACT, int NN, typename TOUT>
__global__ void
__launch_bounds__(256, (((9 * CIN + 31) / 32 * 32 / 32) <= 9) ? 4 : 2)
sconv_vm(const bf16* __restrict__ x, const int* __restrict__ idx,
         const bf16* __restrict__ Wfrag, const float* __restrict__ bias,
         TOUT* __restrict__ y)
{
    constexpr int KP  = (9 * CIN + 31) / 32 * 32;
    constexpr int NKK = KP / 32;
    constexpr int NCB = COP / 16;
    constexpr int CH  = (NKK <= 9) ? NKK : 6;     // 5 (CIN16), 9 (CIN32), 6 (CIN64/128)
    constexpr int NCHUNK = NKK / CH;              // 1, 1, 3, 6
    constexpr int NBUF = (NCHUNK > 1) ? 2 : 1;

    const int t = threadIdx.x, w = t >> 6, lane = t & 63;
    const int n = blockIdx.x * 4 + w;
    if (n >= NN) return;
    const int col0 = lane & 15, kh = lane >> 4;

    int jn[9];
    #pragma unroll
    for (int s = 0; s < 9; ++s) jn[s] = idx[n * 9 + s];

    f32x4 acc[2][NCB];
    #pragma unroll
    for (int cb = 0; cb < NCB; ++cb) {
        int col = cb * 16 + col0;
        float bv = (col < COUT) ? bias[col] : 0.f;
        acc[0][cb] = (f32x4){bv, bv, bv, bv};
        acc[1][cb] = (f32x4){bv, bv, bv, bv};
    }

    const short8_t z8 = {0, 0, 0, 0, 0, 0, 0, 0};
    auto loadA = [&](int kk, short8_t& a0, short8_t& a1) {
        a0 = z8; a1 = z8;
        if constexpr (CIN == 16) {
            const int hi = kh >> 1;
            const int ch = (kh & 1) * 8;
            if (kk < 4) {
                int j = hi ? jn[2 * kk + 1] : jn[2 * kk];
                const bf16* base = x + (size_t)j * 512 + ch;
                a0 = *(const short8_t*)(base + col0 * 16);
                a1 = *(const short8_t*)(base + 256 + col0 * 16);
            } else if (!hi) {
                int j = jn[8];
                const bf16* base = x + (size_t)j * 512 + ch;
                a0 = *(const short8_t*)(base + col0 * 16);
                a1 = *(const short8_t*)(base + 256 + col0 * 16);
            }
        } else {
            constexpr int SPK = CIN / 32;
            const int j = jn[kk / SPK];
            const int ch = (kk % SPK) * 32 + kh * 8;
            const bf16* base = x + (size_t)j * (32 * CIN) + ch;
            a0 = *(const short8_t*)(base + col0 * CIN);
            a1 = *(const short8_t*)(base + (16 + col0) * CIN);
        }
    };

    short8_t bufA[NBUF][2 * CH];
    #pragma unroll
    for (int q = 0; q < CH; ++q)
        loadA(q, bufA[0][2 * q], bufA[0][2 * q + 1]);

    #pragma unroll
    for (int c = 0; c < NCHUNK; ++c) {
        const int cur = (NBUF > 1) ? (c & 1) : 0;
        if (c + 1 < NCHUNK) {
            const int nxt = (NBUF > 1) ? ((c + 1) & 1) : 0;
            #pragma unroll
            for (int q = 0; q < CH; ++q)
                loadA((c + 1) * CH + q, bufA[nxt][2 * q], bufA[nxt][2 * q + 1]);
        }
        #pragma unroll
        for (int q = 0; q < CH; ++q) {
            const int kk = c * CH + q;
            #pragma unroll
            for (int cb = 0; cb < NCB; ++cb) {
                short8_t bfr = *(const short8_t*)(Wfrag + ((size_t)(cb * NKK + kk) * 64 + lane) * 8);
                acc[0][cb] = __builtin_amdgcn_mfma_f32_16x16x32_bf16(bufA[cur][2 * q],     bfr, acc[0][cb], 0, 0, 0);
                acc[1][cb] = __builtin_amdgcn_mfma_f32_16x16x32_bf16(bufA[cur][2 * q + 1], bfr, acc[1][cb], 0, 0, 0);
            }
        }
    }

    #pragma unroll
    for (int f = 0; f < 2; ++f) {
        #pragma unroll
        for (int cb = 0; cb < NCB; ++cb) {
            int col = cb * 16 + col0;
            if (col < COUT) {
                #pragma unroll
                for (int i = 0; i < 4; ++i) {
                    int b = f * 16 + kh * 4 + i;
                    float v = acc[f][cb][i];
                    if (ACT) v = v > 0.f ? v : expm1f(v);
                    TOUT* dst = &y[((size_t)n * 32 + b) * COUT + col];
                    if constexpr (__is_same(TOUT, float)) *dst = v;
                    else *dst = __float2bfloat16(v);
                }
            }
        }
    }
}

// ---- Pool (vertex-major): y[(m*32+b)*C+c] = sum_j v*x[(col*32+b)*C+c] ------
template<int C8>
__global__ void __launch_bounds__(256)
pool_vm(const bf16* __restrict__ x, const int* __restrict__ cols,
        const float* __restrict__ vals, bf16* __restrict__ y, int M)
{
    constexpr int BC8 = 32 * C8;
    int tid = blockIdx.x * 256 + threadIdx.x;
    if (tid >= M * BC8) return;
    int m = tid / BC8;
    int e = tid - m * BC8;
    const uint4* xv = (const uint4*)x;
    float acc[8];
    #pragma unroll
    for (int q = 0; q < 8; ++q) acc[q] = 0.f;
    #pragma unroll
    for (int j = 0; j < 4; ++j) {
        int col = cols[m * 4 + j];
        float v = vals[m * 4 + j];
        uint4 u = xv[(size_t)col * BC8 + e];
        const bf16* hh = (const bf16*)&u;
        #pragma unroll
        for (int q = 0; q < 8; ++q)
            acc[q] = fmaf(v, __bfloat162float(hh[q]), acc[q]);
    }
    uint4 o;
    bf16* oh = (bf16*)&o;
    #pragma unroll
    for (int q = 0; q < 8; ++q) oh[q] = __float2bfloat16(acc[q]);
    ((uint4*)y)[(size_t)m * BC8 + e] = o;
}

// ---- mu split-K: block = vertex n ; h is (200, 32, 128) vertex-major -------
__global__ void __launch_bounds__(256)
mu_partial_kernel(const bf16* __restrict__ h, const float* __restrict__ W,
                  float* __restrict__ partial)
{
    __shared__ float hs[4096];
    const int t = threadIdx.x;
    const int nb = blockIdx.x;
    const bf16* hb = h + (size_t)nb * 4096;
    for (int e = t; e < 512; e += 256) {
        short8_t v = *(const short8_t*)(hb + e * 8);
        #pragma unroll
        for (int q = 0; q < 8; ++q)
            hs[e * 8 + q] = __bfloat162float(((const bf16*)&v)[q]);
    }
    __syncthreads();
    const int co = t & 127;
    const int bh = t >> 7;
    float acc[16];
    #pragma unroll
    for (int i = 0; i < 16; ++i) acc[i] = 0.f;
    const int k0 = nb * 128;
    for (int k = 0; k < 128; ++k) {
        float wv = W[(size_t)(k0 + k) * 128 + co];
        #pragma unroll
        for (int i = 0; i < 16; ++i)
            acc[i] = fmaf(hs[(bh * 16 + i) * 128 + k], wv, acc[i]);
    }
    float* pb = partial + (size_t)nb * 4096;
    #pragma unroll
    for (int i = 0; i < 16; ++i)
        pb[(bh * 16 + i) * 128 + co] = acc[i];
}

__global__ void __launch_bounds__(256)
mu_reduce_kernel(const float* __restrict__ partial, const float* __restrict__ bias,
                 float* __restrict__ z, float* __restrict__ out_z,
                 float* __restrict__ out_mu)
{
    const int i = blockIdx.x * 256 + threadIdx.x;
    const int co = i & 127;
    float a0 = 0.f, a1 = 0.f, a2 = 0.f, a3 = 0.f;
    #pragma unroll 4
    for (int c = 0; c < 200; c += 4) {
        a0 += partial[(size_t)c * 4096 + i];
        a1 += partial[(size_t)(c + 1) * 4096 + i];
        a2 += partial[(size_t)(c + 2) * 4096 + i];
        a3 += partial[(size_t)(c + 3) * 4096 + i];
    }
    float acc = (a0 + a1) + (a2 + a3) + bias[co];
    float m = 1.f / (1.f + expf(-acc));
    z[i] = m;
    out_z[i] = m;
    out_mu[i] = m;
}

// ---- d0 = z @ deW0 + deb0, output vertex-major (200, 32, 128) --------------
__global__ void __launch_bounds__(256)
de0_kernel(const float* __restrict__ z, const float* __restrict__ W,
           const float* __restrict__ bias, bf16* __restrict__ d)
{
    __shared__ float zs[BATCH * 128];
    const int t = threadIdx.x;
    for (int e = t; e < BATCH * 128; e += 256) zs[e] = z[e];
    __syncthreads();
    const int j = blockIdx.x * 256 + t;
    float bj = bias[j];
    float acc[BATCH];
    #pragma unroll
    for (int b = 0; b < BATCH; ++b) acc[b] = bj;
    for (int k = 0; k < 128; ++k) {
        float w = W[k * 25600 + j];
        #pragma unroll
        for (int b = 0; b < BATCH; ++b)
            acc[b] = fmaf(zs[b * 128 + k], w, acc[b]);
    }
    const int nn = j >> 7, c = j & 127;
    #pragma unroll
    for (int b = 0; b < BATCH; ++b)
        d[(size_t)nn * 4096 + b * 128 + c] = __float2bfloat16(acc[b]);
}

extern "C" void kernel_launch(void* const* d_in, const int* in_sizes, int n_in,
                              void* d_out, int out_size, void* d_ws, size_t ws_size,
                              hipStream_t stream)
{
    const float* x = (const float*)d_in[0];
    const int*   sp[4];
    const int*   dn_cols[4];
    const float* dn_vals[4];
    const int*   up_cols[4];
    const float* up_vals[4];
    const float* enW[4];
    const float* enb[4];
    for (int l = 0; l < 4; ++l) {
        int base = 1 + 9 * l;
        sp[l]      = (const int*)d_in[base + 0];
        dn_cols[l] = (const int*)d_in[base + 2];
        dn_vals[l] = (const float*)d_in[base + 3];
        up_cols[l] = (const int*)d_in[base + 5];
        up_vals[l] = (const float*)d_in[base + 6];
        enW[l]     = (const float*)d_in[base + 7];
        enb[l]     = (const float*)d_in[base + 8];
    }
    const float* muW  = (const float*)d_in[37];
    const float* mub  = (const float*)d_in[38];
    const float* deW0 = (const float*)d_in[39];
    const float* deb0 = (const float*)d_in[40];
    const float* dW[4]  = { (const float*)d_in[41], (const float*)d_in[43],
                            (const float*)d_in[45], (const float*)d_in[47] };
    const float* db[4]  = { (const float*)d_in[42], (const float*)d_in[44],
                            (const float*)d_in[46], (const float*)d_in[48] };
    const float* outW = (const float*)d_in[49];
    const float* outb = (const float*)d_in[50];

    char* ws = (char*)d_ws;
    bf16*  A  = (bf16*)ws;                        // [0, 51.2MB)
    bf16*  Bb = (bf16*)(ws + 51200000);           // [51.2MB, 153.6MB)
    bf16*  xT = (bf16*)(ws + 51200000);           // overlaps Bb (dead then)
    float* outVM = (float*)(ws + 51200000);       // overlaps Bb (dead then)
    float* Z  = (float*)(ws + 153600000);
    bf16*  wEN0 = (bf16*)(ws + 153600000 + 16384);
    bf16*  wOUT = wEN0 + 512;

    float* outF   = (float*)d_out;
    float* out_z  = outF + 4800000;
    float* out_mu = outF + 4804096;

    bf16*  wsc  = (bf16*)d_out;
    bf16*  wEN1 = wsc;
    bf16*  wEN2 = wsc + 5120;
    bf16*  wEN3 = wsc + 23552;
    bf16*  wDW0 = wsc + 97280;
    bf16*  wDW1 = wsc + 244736;
    bf16*  wDW2 = wsc + 318464;
    bf16*  wDW3 = wsc + 336896;
    float* muPart = outF + 1000000;

    WcvAll wp;
    const float* srcs[9] = {enW[0], enW[1], enW[2], enW[3], dW[0], dW[1], dW[2], dW[3], outW};
    bf16* dsts[9] = {wEN0, wEN1, wEN2, wEN3, wDW0, wDW1, wDW2, wDW3, wOUT};
    int Ks[9]   = {27, 144, 288, 576, 1152, 1152, 576, 288, 144};
    int COs[9]  = {16, 32, 64, 128, 128, 64, 32, 16, 3};
    int KPs[9]  = {32, 160, 288, 576, 1152, 1152, 576, 288, 160};
    int COPs[9] = {16, 32, 64, 128, 128, 64, 32, 16, 16};
    int off = 0;
    for (int s = 0; s < 9; ++s) {
        wp.W[s] = srcs[s]; wp.dst[s] = dsts[s];
        wp.K[s] = Ks[s]; wp.CO[s] = COs[s]; wp.KP[s] = KPs[s];
        wp.off[s] = off; off += COPs[s] * KPs[s];
    }
    wp.off[9] = off;
    auto cdiv = [](int a, int b) { return (a + b - 1) / b; };
    wconv_all_kernel<<<cdiv(off, 256), 256, 0, stream>>>(wp);

    // -------- input transpose to vertex-major --------
    xpose_in_kernel<<<NS0 / 8, 256, 0, stream>>>(x, xT);

    // -------- encoder (activations vertex-major (N, 32, C)) --------
    sconv_enc0<<<NS0 / 2, 256, 0, stream>>>(xT, sp[0], wEN0, enb[0], A);
    pool_vm<2><<<cdiv(NS1 * 64, 256), 256, 0, stream>>>(A, dn_cols[0], dn_vals[0], Bb, NS1);
    sconv_vm<16, 32, 32, 1, NS1, bf16><<<cdiv(NS1, 4), 256, 0, stream>>>(Bb, sp[1], wEN1, enb[1], A);
    pool_vm<4><<<cdiv(NS2 * 128, 256), 256, 0, stream>>>(A, dn_cols[1], dn_vals[1], Bb, NS2);
    sconv_vm<32, 64, 64, 1, NS2, bf16><<<cdiv(NS2, 4), 256, 0, stream>>>(Bb, sp[2], wEN2, enb[2], A);
    pool_vm<8><<<cdiv(NS3 * 256, 256), 256, 0, stream>>>(A, dn_cols[2], dn_vals[2], Bb, NS3);
    sconv_vm<64, 128, 128, 1, NS3, bf16><<<cdiv(NS3, 4), 256, 0, stream>>>(Bb, sp[3], wEN3, enb[3], A);
    pool_vm<16><<<cdiv(NS4 * 512, 256), 256, 0, stream>>>(A, dn_cols[3], dn_vals[3], Bb, NS4);

    // -------- latent --------
    mu_partial_kernel<<<200, 256, 0, stream>>>(Bb, muW, muPart);
    mu_reduce_kernel<<<16, 256, 0, stream>>>(muPart, mub, Z, out_z, out_mu);
    de0_kernel<<<25600 / 256, 256, 0, stream>>>(Z, deW0, deb0, A);

    // -------- decoder --------
    pool_vm<16><<<cdiv(NS3 * 512, 256), 256, 0, stream>>>(A, up_cols[3], up_vals[3], Bb, NS3);
    sconv_vm<128, 128, 128, 1, NS3, bf16><<<cdiv(NS3, 4), 256, 0, stream>>>(Bb, sp[3], wDW0, db[0], A);
    pool_vm<16><<<cdiv(NS2 * 512, 256), 256, 0, stream>>>(A, up_cols[2], up_vals[2], Bb, NS2);
    sconv_vm<128, 64, 64, 1, NS2, bf16><<<cdiv(NS2, 4), 256, 0, stream>>>(Bb, sp[2], wDW1, db[1], A);
    pool_vm<8><<<cdiv(NS1 * 256, 256), 256, 0, stream>>>(A, up_cols[1], up_vals[1], Bb, NS1);
    sconv_vm<64, 32, 32, 1, NS1, bf16><<<cdiv(NS1, 4), 256, 0, stream>>>(Bb, sp[1], wDW2, db[2], A);
    pool_vm<4><<<cdiv(NS0 * 128, 256), 256, 0, stream>>>(A, up_cols[0], up_vals[0], Bb, NS0);
    sconv_vm<32, 16, 16, 1, NS0, bf16><<<cdiv(NS0, 4), 256, 0, stream>>>(Bb, sp[0], wDW3, db[3], A);

    // -------- output conv: vertex-major fp32 into ws, then transpose --------
    sconv_vm<16, 3, 16, 0, NS0, float><<<cdiv(NS0, 4), 256, 0, stream>>>(A, sp[0], wOUT, outb, outVM);
    xpose_out_kernel<<<NS0 / 8, 256, 0, stream>>>(outVM, outF);
}

// Round 9
// 746.000 us; speedup vs baseline: 9.1891x; 1.0144x over previous
//
#include <hip/hip_runtime.h>
#include <hip/hip_bf16.h>
#include <math.h>

#define NS0 50000
#define NS1 12500
#define NS2 3125
#define NS3 800
#define NS4 200
#define BATCH 32
#define SLEN 9

typedef __hip_bfloat16 bf16;
typedef __attribute__((ext_vector_type(8))) short short8_t;
typedef __attribute__((ext_vector_type(4))) float f32x4;

// ---- fused W conversion: fp32 (K,CO) -> bf16 MFMA-fragment-packed ----------
struct WcvAll {
    const float* W[9];
    bf16* dst[9];
    int K[9], CO[9], KP[9];
    int off[10];
};

__global__ void __launch_bounds__(256)
wconv_all_kernel(WcvAll p)
{
    int gid = blockIdx.x * 256 + threadIdx.x;
    if (gid >= p.off[9]) return;
    int seg = 0;
    #pragma unroll
    for (int s = 1; s < 9; ++s) seg += (gid >= p.off[s]);
    int local = gid - p.off[seg];
    int NKK = p.KP[seg] >> 5;
    int jj   = local & 7;
    int g8   = local >> 3;
    int lane = g8 & 63;
    int blk  = g8 >> 6;
    int kk   = blk % NKK;
    int cb   = blk / NKK;
    int col0 = lane & 15, kh = lane >> 4;
    int co = cb * 16 + col0;
    int k  = kk * 32 + kh * 8 + jj;
    float v = (k < p.K[seg] && co < p.CO[seg]) ? p.W[seg][k * p.CO[seg] + co] : 0.f;
    p.dst[seg][local] = __float2bfloat16(v);
}

// ---- transpose x: fp32 (B, N0, 3) -> bf16 (N0, 32, 3), LDS-tiled -----------
__global__ void __launch_bounds__(256)
xpose_in_kernel(const float* __restrict__ x, bf16* __restrict__ xT)
{
    __shared__ short ldsb[256 * 3];
    const int t = threadIdx.x;
    const int n0 = blockIdx.x * 8;
    const int b = t >> 3, v = t & 7;
    const float* src = x + ((size_t)b * NS0 + n0 + v) * 3;
    short* d = &ldsb[(v * 32 + b) * 3];
    d[0] = __bfloat16_as_short(__float2bfloat16(src[0]));
    d[1] = __bfloat16_as_short(__float2bfloat16(src[1]));
    d[2] = __bfloat16_as_short(__float2bfloat16(src[2]));
    __syncthreads();
    short* dst = (short*)xT + ((size_t)n0 * 32 + t) * 3;
    dst[0] = ldsb[t * 3 + 0];
    dst[1] = ldsb[t * 3 + 1];
    dst[2] = ldsb[t * 3 + 2];
}

// ---- enc0: CIN=3 LDS-staged MFMA from vertex-major xT (N0, 32, 3) ----------
__global__ void __launch_bounds__(256)
sconv_enc0(const bf16* __restrict__ xT, const int* __restrict__ idx,
           const bf16* __restrict__ Wfrag, const float* __restrict__ bias,
           bf16* __restrict__ y)
{
    __shared__ short lds[64 * 40];
    const int t = threadIdx.x;
    const int n0 = blockIdx.x * 2;

    for (int e = t; e < 64 * 5; e += 256) {
        int r = e / 5, k = 27 + (e - r * 5);
        lds[r * 40 + k] = 0;
    }
    for (int e = t; e < 2 * 9 * 32; e += 256) {
        int v = e / 288;
        int rem = e - v * 288;
        int s = rem >> 5, b = rem & 31;
        int j = idx[(n0 + v) * 9 + s];
        const short* src = (const short*)(xT + (size_t)j * 96 + b * 3);
        short* dst = &lds[(v * 32 + b) * 40 + s * 3];
        dst[0] = src[0];
        dst[1] = src[1];
        dst[2] = src[2];
    }
    __syncthreads();

    const int w = t >> 6, lane = t & 63;
    const int col0 = lane & 15, kh = lane >> 4;
    const int rbase = w * 16;
    float bv = bias[col0];
    f32x4 acc = (f32x4){bv, bv, bv, bv};
    short8_t bfr = *(const short8_t*)(Wfrag + (size_t)lane * 8);
    short8_t afr = *(const short8_t*)&lds[(rbase + col0) * 40 + kh * 8];
    acc = __builtin_amdgcn_mfma_f32_16x16x32_bf16(afr, bfr, acc, 0, 0, 0);
    #pragma unroll
    for (int i = 0; i < 4; ++i) {
        int rl = rbase + kh * 4 + i;
        float v = acc[i];
        v = v > 0.f ? v : expm1f(v);
        y[((size_t)n0 * 32 + rl) * 16 + col0] = __float2bfloat16(v);
    }
}

// ---- small-CIN direct conv (CIN 16/32): FULL load burst pinned by ----------
// sched_barrier(0) so all gathers are in flight before the MFMA block.
// XPOSE=1: fused output transpose to fp32 (B, N0, 3).
template<int CIN, int COUT, int COP, int ACT, int NN, int XPOSE, typename TOUT>
__global__ void __launch_bounds__(256, 4)
sconv_small(const bf16* __restrict__ x, const int* __restrict__ idx,
            const bf16* __restrict__ Wfrag, const float* __restrict__ bias,
            TOUT* __restrict__ y)
{
    constexpr int KP  = (9 * CIN + 31) / 32 * 32;
    constexpr int NKK = KP / 32;                  // 5 (CIN16), 9 (CIN32)
    constexpr int NCB = COP / 16;
    constexpr int XD  = XPOSE ? 4 : 1;
    __shared__ float xls[XD][32][3];

    const int t = threadIdx.x, w = t >> 6, lane = t & 63;
    const int n = blockIdx.x * 4 + w;
    if (n >= NN) return;                          // XPOSE grids are exact (no barrier skipped)
    const int col0 = lane & 15, kh = lane >> 4;

    int jn[9];
    #pragma unroll
    for (int s = 0; s < 9; ++s) jn[s] = idx[n * 9 + s];

    f32x4 acc[2][NCB];
    #pragma unroll
    for (int cb = 0; cb < NCB; ++cb) {
        int col = cb * 16 + col0;
        float bv = (col < COUT) ? bias[col] : 0.f;
        acc[0][cb] = (f32x4){bv, bv, bv, bv};
        acc[1][cb] = (f32x4){bv, bv, bv, bv};
    }

    const short8_t z8 = {0, 0, 0, 0, 0, 0, 0, 0};
    short8_t fa[2 * NKK];
    #pragma unroll
    for (int kk = 0; kk < NKK; ++kk) {
        short8_t a0 = z8, a1 = z8;
        if constexpr (CIN == 16) {
            const int hi = kh >> 1;
            const int ch = (kh & 1) * 8;
            if (kk < 4) {
                int j = hi ? jn[2 * kk + 1] : jn[2 * kk];
                const bf16* base = x + (size_t)j * 512 + ch;
                a0 = *(const short8_t*)(base + col0 * 16);
                a1 = *(const short8_t*)(base + 256 + col0 * 16);
            } else if (!hi) {
                int j = jn[8];
                const bf16* base = x + (size_t)j * 512 + ch;
                a0 = *(const short8_t*)(base + col0 * 16);
                a1 = *(const short8_t*)(base + 256 + col0 * 16);
            }
        } else {                                  // CIN == 32
            const int j = jn[kk];
            const bf16* base = x + (size_t)j * 1024 + kh * 8;
            a0 = *(const short8_t*)(base + col0 * 32);
            a1 = *(const short8_t*)(base + (16 + col0) * 32);
        }
        fa[2 * kk] = a0;
        fa[2 * kk + 1] = a1;
    }
    __builtin_amdgcn_sched_barrier(0);            // all gathers issued before MFMAs

    #pragma unroll
    for (int kk = 0; kk < NKK; ++kk) {
        #pragma unroll
        for (int cb = 0; cb < NCB; ++cb) {
            short8_t bfr = *(const short8_t*)(Wfrag + ((size_t)(cb * NKK + kk) * 64 + lane) * 8);
            acc[0][cb] = __builtin_amdgcn_mfma_f32_16x16x32_bf16(fa[2 * kk],     bfr, acc[0][cb], 0, 0, 0);
            acc[1][cb] = __builtin_amdgcn_mfma_f32_16x16x32_bf16(fa[2 * kk + 1], bfr, acc[1][cb], 0, 0, 0);
        }
    }

    if constexpr (XPOSE) {
        // stage (v=w, b, c<3) in LDS, then coalesced write of fp32 (B, N0, 3)
        if (col0 < 3) {
            #pragma unroll
            for (int f = 0; f < 2; ++f)
                #pragma unroll
                for (int i = 0; i < 4; ++i)
                    xls[w][f * 16 + kh * 4 + i][col0] = acc[f][0][i];
        }
        __syncthreads();
        const int n0 = blockIdx.x * 4;
        for (int e = t; e < 384; e += 256) {
            int b = e / 12, rem = e - b * 12;
            int v = rem / 3, c = rem - v * 3;
            y[((size_t)b * NN + n0 + v) * 3 + c] = xls[v][b][c];
        }
    } else {
        #pragma unroll
        for (int f = 0; f < 2; ++f) {
            #pragma unroll
            for (int cb = 0; cb < NCB; ++cb) {
                int col = cb * 16 + col0;
                if (col < COUT) {
                    #pragma unroll
                    for (int i = 0; i < 4; ++i) {
                        int b = f * 16 + kh * 4 + i;
                        float v = acc[f][cb][i];
                        if (ACT) v = v > 0.f ? v : expm1f(v);
                        y[((size_t)n * 32 + b) * COUT + col] = __float2bfloat16(v);
                    }
                }
            }
        }
    }
}

// ---- big-CIN direct conv (CIN 64/128): pinned bursts of 9 k-steps ----------
template<int CIN, int COUT, int COP, int ACT, int NN>
__global__ void __launch_bounds__(256, (COP >= 128 || CIN >= 128) ? 2 : 4)
sconv_big(const bf16* __restrict__ x, const int* __restrict__ idx,
          const bf16* __restrict__ Wfrag, const float* __restrict__ bias,
          bf16* __restrict__ y)
{
    constexpr int KP  = 9 * CIN;                  // already /32
    constexpr int NKK = KP / 32;                  // 18 or 36
    constexpr int NCB = COP / 16;
    constexpr int CH  = 9;
    constexpr int NCHUNK = NKK / CH;              // 2 or 4

    const int t = threadIdx.x, w = t >> 6, lane = t & 63;
    const int n = blockIdx.x * 4 + w;
    if (n >= NN) return;
    const int col0 = lane & 15, kh = lane >> 4;

    int jn[9];
    #pragma unroll
    for (int s = 0; s < 9; ++s) jn[s] = idx[n * 9 + s];

    f32x4 acc[2][NCB];
    #pragma unroll
    for (int cb = 0; cb < NCB; ++cb) {
        int col = cb * 16 + col0;
        float bv = (col < COUT) ? bias[col] : 0.f;
        acc[0][cb] = (f32x4){bv, bv, bv, bv};
        acc[1][cb] = (f32x4){bv, bv, bv, bv};
    }

    constexpr int SPK = CIN / 32;
    short8_t fa[2 * CH];
    #pragma unroll
    for (int c = 0; c < NCHUNK; ++c) {
        #pragma unroll
        for (int q = 0; q < CH; ++q) {
            const int kk = c * CH + q;
            const int j = jn[kk / SPK];
            const int ch = (kk % SPK) * 32 + kh * 8;
            const bf16* base = x + (size_t)j * (32 * CIN) + ch;
            fa[2 * q]     = *(const short8_t*)(base + col0 * CIN);
            fa[2 * q + 1] = *(const short8_t*)(base + (16 + col0) * CIN);
        }
        __builtin_amdgcn_sched_barrier(0);        // burst of 18 gathers in flight
        #pragma unroll
        for (int q = 0; q < CH; ++q) {
            const int kk = c * CH + q;
            #pragma unroll
            for (int cb = 0; cb < NCB; ++cb) {
                short8_t bfr = *(const short8_t*)(Wfrag + ((size_t)(cb * NKK + kk) * 64 + lane) * 8);
                acc[0][cb] = __builtin_amdgcn_mfma_f32_16x16x32_bf16(fa[2 * q],     bfr, acc[0][cb], 0, 0, 0);
                acc[1][cb] = __builtin_amdgcn_mfma_f32_16x16x32_bf16(fa[2 * q + 1], bfr, acc[1][cb], 0, 0, 0);
            }
        }
    }

    #pragma unroll
    for (int f = 0; f < 2; ++f) {
        #pragma unroll
        for (int cb = 0; cb < NCB; ++cb) {
            int col = cb * 16 + col0;
            if (col < COUT) {
                #pragma unroll
                for (int i = 0; i < 4; ++i) {
                    int b = f * 16 + kh * 4 + i;
                    float v = acc[f][cb][i];
                    if (ACT) v = v > 0.f ? v : expm1f(v);
                    y[((size_t)n * 32 + b) * COUT + col] = __float2bfloat16(v);
                }
            }
        }
    }
}

// ---- Pool (vertex-major): y[(m*32+b)*C+c] = sum_j v*x[(col*32+b)*C+c] ------
template<int C8>
__global__ void __launch_bounds__(256)
pool_vm(const bf16* __restrict__ x, const int* __restrict__ cols,
        const float* __restrict__ vals, bf16* __restrict__ y, int M)
{
    constexpr int BC8 = 32 * C8;
    int tid = blockIdx.x * 256 + threadIdx.x;
    if (tid >= M * BC8) return;
    int m = tid / BC8;
    int e = tid - m * BC8;
    const uint4* xv = (const uint4*)x;
    float acc[8];
    #pragma unroll
    for (int q = 0; q < 8; ++q) acc[q] = 0.f;
    #pragma unroll
    for (int j = 0; j < 4; ++j) {
        int col = cols[m * 4 + j];
        float v = vals[m * 4 + j];
        uint4 u = xv[(size_t)col * BC8 + e];
        const bf16* hh = (const bf16*)&u;
        #pragma unroll
        for (int q = 0; q < 8; ++q)
            acc[q] = fmaf(v, __bfloat162float(hh[q]), acc[q]);
    }
    uint4 o;
    bf16* oh = (bf16*)&o;
    #pragma unroll
    for (int q = 0; q < 8; ++q) oh[q] = __float2bfloat16(acc[q]);
    ((uint4*)y)[(size_t)m * BC8 + e] = o;
}

// ---- mu split-K ------------------------------------------------------------
__global__ void __launch_bounds__(256)
mu_partial_kernel(const bf16* __restrict__ h, const float* __restrict__ W,
                  float* __restrict__ partial)
{
    __shared__ float hs[4096];
    const int t = threadIdx.x;
    const int nb = blockIdx.x;
    const bf16* hb = h + (size_t)nb * 4096;
    for (int e = t; e < 512; e += 256) {
        short8_t v = *(const short8_t*)(hb + e * 8);
        #pragma unroll
        for (int q = 0; q < 8; ++q)
            hs[e * 8 + q] = __bfloat162float(((const bf16*)&v)[q]);
    }
    __syncthreads();
    const int co = t & 127;
    const int bh = t >> 7;
    float acc[16];
    #pragma unroll
    for (int i = 0; i < 16; ++i) acc[i] = 0.f;
    const int k0 = nb * 128;
    for (int k = 0; k < 128; ++k) {
        float wv = W[(size_t)(k0 + k) * 128 + co];
        #pragma unroll
        for (int i = 0; i < 16; ++i)
            acc[i] = fmaf(hs[(bh * 16 + i) * 128 + k], wv, acc[i]);
    }
    float* pb = partial + (size_t)nb * 4096;
    #pragma unroll
    for (int i = 0; i < 16; ++i)
        pb[(bh * 16 + i) * 128 + co] = acc[i];
}

__global__ void __launch_bounds__(256)
mu_reduce_kernel(const float* __restrict__ partial, const float* __restrict__ bias,
                 float* __restrict__ z, float* __restrict__ out_z,
                 float* __restrict__ out_mu)
{
    const int i = blockIdx.x * 256 + threadIdx.x;
    const int co = i & 127;
    float a0 = 0.f, a1 = 0.f, a2 = 0.f, a3 = 0.f;
    #pragma unroll 4
    for (int c = 0; c < 200; c += 4) {
        a0 += partial[(size_t)c * 4096 + i];
        a1 += partial[(size_t)(c + 1) * 4096 + i];
        a2 += partial[(size_t)(c + 2) * 4096 + i];
        a3 += partial[(size_t)(c + 3) * 4096 + i];
    }
    float acc = (a0 + a1) + (a2 + a3) + bias[co];
    float m = 1.f / (1.f + expf(-acc));
    z[i] = m;
    out_z[i] = m;
    out_mu[i] = m;
}

// ---- d0 = z @ deW0 + deb0, output vertex-major (200, 32, 128) --------------
__global__ void __launch_bounds__(256)
de0_kernel(const float* __restrict__ z, const float* __restrict__ W,
           const float* __restrict__ bias, bf16* __restrict__ d)
{
    __shared__ float zs[BATCH * 128];
    const int t = threadIdx.x;
    for (int e = t; e < BATCH * 128; e += 256) zs[e] = z[e];
    __syncthreads();
    const int j = blockIdx.x * 256 + t;
    float bj = bias[j];
    float acc[BATCH];
    #pragma unroll
    for (int b = 0; b < BATCH; ++b) acc[b] = bj;
    for (int k = 0; k < 128; ++k) {
        float w = W[k * 25600 + j];
        #pragma unroll
        for (int b = 0; b < BATCH; ++b)
            acc[b] = fmaf(zs[b * 128 + k], w, acc[b]);
    }
    const int nn = j >> 7, c = j & 127;
    #pragma unroll
    for (int b = 0; b < BATCH; ++b)
        d[(size_t)nn * 4096 + b * 128 + c] = __float2bfloat16(acc[b]);
}

extern "C" void kernel_launch(void* const* d_in, const int* in_sizes, int n_in,
                              void* d_out, int out_size, void* d_ws, size_t ws_size,
                              hipStream_t stream)
{
    const float* x = (const float*)d_in[0];
    const int*   sp[4];
    const int*   dn_cols[4];
    const float* dn_vals[4];
    const int*   up_cols[4];
    const float* up_vals[4];
    const float* enW[4];
    const float* enb[4];
    for (int l = 0; l < 4; ++l) {
        int base = 1 + 9 * l;
        sp[l]      = (const int*)d_in[base + 0];
        dn_cols[l] = (const int*)d_in[base + 2];
        dn_vals[l] = (const float*)d_in[base + 3];
        up_cols[l] = (const int*)d_in[base + 5];
        up_vals[l] = (const float*)d_in[base + 6];
        enW[l]     = (const float*)d_in[base + 7];
        enb[l]     = (const float*)d_in[base + 8];
    }
    const float* muW  = (const float*)d_in[37];
    const float* mub  = (const float*)d_in[38];
    const float* deW0 = (const float*)d_in[39];
    const float* deb0 = (const float*)d_in[40];
    const float* dW[4]  = { (const float*)d_in[41], (const float*)d_in[43],
                            (const float*)d_in[45], (const float*)d_in[47] };
    const float* db[4]  = { (const float*)d_in[42], (const float*)d_in[44],
                            (const float*)d_in[46], (const float*)d_in[48] };
    const float* outW = (const float*)d_in[49];
    const float* outb = (const float*)d_in[50];

    char* ws = (char*)d_ws;
    bf16*  A  = (bf16*)ws;                        // [0, 51.2MB)
    bf16*  Bb = (bf16*)(ws + 51200000);           // [51.2MB, 153.6MB)
    bf16*  xT = (bf16*)(ws + 51200000);           // overlaps Bb (dead then)
    float* Z  = (float*)(ws + 153600000);
    bf16*  wEN0 = (bf16*)(ws + 153600000 + 16384);
    bf16*  wOUT = wEN0 + 512;

    float* outF   = (float*)d_out;
    float* out_z  = outF + 4800000;
    float* out_mu = outF + 4804096;

    bf16*  wsc  = (bf16*)d_out;
    bf16*  wEN1 = wsc;
    bf16*  wEN2 = wsc + 5120;
    bf16*  wEN3 = wsc + 23552;
    bf16*  wDW0 = wsc + 97280;
    bf16*  wDW1 = wsc + 244736;
    bf16*  wDW2 = wsc + 318464;
    bf16*  wDW3 = wsc + 336896;
    float* muPart = outF + 1000000;

    WcvAll wp;
    const float* srcs[9] = {enW[0], enW[1], enW[2], enW[3], dW[0], dW[1], dW[2], dW[3], outW};
    bf16* dsts[9] = {wEN0, wEN1, wEN2, wEN3, wDW0, wDW1, wDW2, wDW3, wOUT};
    int Ks[9]   = {27, 144, 288, 576, 1152, 1152, 576, 288, 144};
    int COs[9]  = {16, 32, 64, 128, 128, 64, 32, 16, 3};
    int KPs[9]  = {32, 160, 288, 576, 1152, 1152, 576, 288, 160};
    int COPs[9] = {16, 32, 64, 128, 128, 64, 32, 16, 16};
    int off = 0;
    for (int s = 0; s < 9; ++s) {
        wp.W[s] = srcs[s]; wp.dst[s] = dsts[s];
        wp.K[s] = Ks[s]; wp.CO[s] = COs[s]; wp.KP[s] = KPs[s];
        wp.off[s] = off; off += COPs[s] * KPs[s];
    }
    wp.off[9] = off;
    auto cdiv = [](int a, int b) { return (a + b - 1) / b; };
    wconv_all_kernel<<<cdiv(off, 256), 256, 0, stream>>>(wp);

    // -------- input transpose to vertex-major --------
    xpose_in_kernel<<<NS0 / 8, 256, 0, stream>>>(x, xT);

    // -------- encoder (activations vertex-major (N, 32, C)) --------
    sconv_enc0<<<NS0 / 2, 256, 0, stream>>>(xT, sp[0], wEN0, enb[0], A);
    pool_vm<2><<<cdiv(NS1 * 64, 256), 256, 0, stream>>>(A, dn_cols[0], dn_vals[0], Bb, NS1);
    sconv_small<16, 32, 32, 1, NS1, 0, bf16><<<cdiv(NS1, 4), 256, 0, stream>>>(Bb, sp[1], wEN1, enb[1], A);
    pool_vm<4><<<cdiv(NS2 * 128, 256), 256, 0, stream>>>(A, dn_cols[1], dn_vals[1], Bb, NS2);
    sconv_small<32, 64, 64, 1, NS2, 0, bf16><<<cdiv(NS2, 4), 256, 0, stream>>>(Bb, sp[2], wEN2, enb[2], A);
    pool_vm<8><<<cdiv(NS3 * 256, 256), 256, 0, stream>>>(A, dn_cols[2], dn_vals[2], Bb, NS3);
    sconv_big<64, 128, 128, 1, NS3><<<cdiv(NS3, 4), 256, 0, stream>>>(Bb, sp[3], wEN3, enb[3], A);
    pool_vm<16><<<cdiv(NS4 * 512, 256), 256, 0, stream>>>(A, dn_cols[3], dn_vals[3], Bb, NS4);

    // -------- latent --------
    mu_partial_kernel<<<200, 256, 0, stream>>>(Bb, muW, muPart);
    mu_reduce_kernel<<<16, 256, 0, stream>>>(muPart, mub, Z, out_z, out_mu);
    de0_kernel<<<25600 / 256, 256, 0, stream>>>(Z, deW0, deb0, A);

    // -------- decoder --------
    pool_vm<16><<<cdiv(NS3 * 512, 256), 256, 0, stream>>>(A, up_cols[3], up_vals[3], Bb, NS3);
    sconv_big<128, 128, 128, 1, NS3><<<cdiv(NS3, 4), 256, 0, stream>>>(Bb, sp[3], wDW0, db[0], A);
    pool_vm<16><<<cdiv(NS2 * 512, 256), 256, 0, stream>>>(A, up_cols[2], up_vals[2], Bb, NS2);
    sconv_big<128, 64, 64, 1, NS2><<<cdiv(NS2, 4), 256, 0, stream>>>(Bb, sp[2], wDW1, db[1], A);
    pool_vm<8><<<cdiv(NS1 * 256, 256), 256, 0, stream>>>(A, up_cols[1], up_vals[1], Bb, NS1);
    sconv_big<64, 32, 32, 1, NS1><<<cdiv(NS1, 4), 256, 0, stream>>>(Bb, sp[1], wDW2, db[2], A);
    pool_vm<4><<<cdiv(NS0 * 128, 256), 256, 0, stream>>>(A, up_cols[0], up_vals[0], Bb, NS0);
    sconv_small<32, 16, 16, 1, NS0, 0, bf16><<<cdiv(NS0, 4), 256, 0, stream>>>(Bb, sp[0], wDW3, db[3], A);

    // -------- output conv: fused transpose, fp32 (B, N0, 3) into d_out ------
    sconv_small<16, 3, 16, 0, NS0, 1, float><<<cdiv(NS0, 4), 256, 0, stream>>>(A, sp[0], wOUT, outb, outF);
}